// Round 1
// baseline (1668.699 us; speedup 1.0000x reference)
//
#include <hip/hip_runtime.h>
#include <cstddef>

// ---------------------------------------------------------------------------
// PatchAttention, algebraically simplified:
//   expx = W_exp @ x + b                          (GEMM, 768x256 @ 256x4096 per n)
//   per window i (win in {2,4,6}), branch = expx channels [i*256,(i+1)*256):
//     v[c,yx]   = expx[br,c,yx] + pos[c,yx]       (never materialized)
//     cnt[yx]   = unfold multiplicity (fold(ones))
//     qdot[yx]  = sum_c ch_wq_w[c]*v + b          (PassA, + ubar accumulation)
//     softmax over unfolded elems == cnt-weighted softmax over pixels (PassB)
//     ubar[c]   = (1/L) sum cnt*v ; spq = softmax(sp_wq_w@ubar+b); w_eff = spq@sp_wv_w
//     uq[c]     = sum cnt*wqpix*v ; wdot[yx] = w_eff . v ; spw = sigmoid(wdot+b_eff) (PassC)
//     z=ch_wv_w@uq+b; wz=ch_wz_w@z+b; LN+sigmoid -> ch_w[c]  (PassD)
//     fold/cnt cancels:  combined[br,c,yx] = expx + v*(ch_w[c]+spw[yx])  (PassE, in-place)
//   out_res = W_res @ combined + b + x            (GEMM)
//   out     = W_fus @ out_res + b                 (GEMM)
// ---------------------------------------------------------------------------

#define HW 4096
#define NB 8

__device__ __forceinline__ int cnt1f(int y, int sh, int kh, int win) {
    int t = y - kh + sh;                 // ceil((y-kh+1)/sh) for positive, else 0
    int lo = t > 0 ? t / sh : 0;
    int hi = min(win - 1, y / sh);
    return hi - lo + 1;
}

__device__ __forceinline__ float waveRedSum(float v) {
    #pragma unroll
    for (int off = 32; off > 0; off >>= 1) v += __shfl_down(v, off, 64);
    return v;
}

// ---------------------------------------------------------------- pos encode
__global__ __launch_bounds__(256) void pos_kernel(float* __restrict__ pos) {
    int idx = blockIdx.x * 256 + threadIdx.x;      // < 1048576
    int row = idx >> 8, col = idx & 255;
    int a = row >> 6, b = row & 63;
    int g = col >> 6, k = col & 63;
    float omega = expf(-(float)k * (9.2103403719761836f / 64.f)); // 10000^(-k/64)
    float arg = (g < 2 ? (float)a : (float)b) * omega;
    pos[idx] = (g & 1) ? cosf(arg) : sinf(arg);
}

__global__ __launch_bounds__(256) void zero_kernel(float* __restrict__ p, int n) {
    int i = blockIdx.x * 256 + threadIdx.x;
    if (i < n) p[i] = 0.f;
}

// ---------------------------------------------------------------- fp32 GEMM
// Out[n,o,p] = sum_c W[o,c] * X[n,c,p] + bias[o] (+ Res[n,o,p])
template<bool ADD_RES>
__global__ __launch_bounds__(256) void gemm1x1(
    const float* __restrict__ W, const float* __restrict__ bias,
    const float* __restrict__ X, const float* __restrict__ Res,
    float* __restrict__ Out, int O, int Cin)
{
    const int P = HW;
    __shared__ __align__(16) float As[16][68];
    __shared__ __align__(16) float Bs[16][64];
    int n = blockIdx.z;
    int p0 = blockIdx.x * 64;
    int o0 = blockIdx.y * 64;
    int tid = threadIdx.x;
    int tx = tid & 15, ty = tid >> 4;
    const float* Xn = X + (size_t)n * Cin * P;
    int lm = tid >> 2, lk = (tid & 3) * 4;   // A loader: 64 rows x 16 cols
    int bk = tid >> 4, bp = (tid & 15) * 4;  // B loader: 16 rows x 64 cols
    float acc[4][4] = {};
    for (int k0 = 0; k0 < Cin; k0 += 16) {
        float4 av = *(const float4*)(W + (size_t)(o0 + lm) * Cin + k0 + lk);
        float4 bv = *(const float4*)(Xn + (size_t)(k0 + bk) * P + p0 + bp);
        __syncthreads();
        As[lk + 0][lm] = av.x; As[lk + 1][lm] = av.y;
        As[lk + 2][lm] = av.z; As[lk + 3][lm] = av.w;
        *(float4*)&Bs[bk][bp] = bv;
        __syncthreads();
        #pragma unroll
        for (int k = 0; k < 16; ++k) {
            float4 a = *(const float4*)&As[k][ty * 4];
            float4 b = *(const float4*)&Bs[k][tx * 4];
            float a4[4] = {a.x, a.y, a.z, a.w};
            float b4[4] = {b.x, b.y, b.z, b.w};
            #pragma unroll
            for (int i = 0; i < 4; ++i)
                #pragma unroll
                for (int j = 0; j < 4; ++j)
                    acc[i][j] = fmaf(a4[i], b4[j], acc[i][j]);
        }
    }
    #pragma unroll
    for (int i = 0; i < 4; ++i) {
        int o = o0 + ty * 4 + i;
        float bo = bias[o];
        float4 r;
        r.x = acc[i][0] + bo; r.y = acc[i][1] + bo;
        r.z = acc[i][2] + bo; r.w = acc[i][3] + bo;
        size_t off = ((size_t)n * O + o) * P + p0 + tx * 4;
        if (ADD_RES) {
            float4 rv = *(const float4*)(Res + off);
            r.x += rv.x; r.y += rv.y; r.z += rv.z; r.w += rv.w;
        }
        *(float4*)(Out + off) = r;
    }
}

// ------------------------------------------------- PassA: qdot + ubar accum
__global__ __launch_bounds__(256) void pass_a(
    const float* __restrict__ expx, const float* __restrict__ pos,
    const float* __restrict__ wq_w, const float* __restrict__ wq_b,
    float* __restrict__ qdot, float* __restrict__ ubar,
    int branch, int sh, int kh, int win)
{
    int n = blockIdx.y;
    int yx = blockIdx.x * 256 + threadIdx.x;
    int y = yx >> 6, x = yx & 63;
    float cntf = (float)(cnt1f(y, sh, kh, win) * cnt1f(x, sh, kh, win));
    const float* eb = expx + ((size_t)(n * 768 + branch * 256)) * HW + yx;
    const float* pb = pos + yx;
    float qacc = 0.f;
    for (int c = 0; c < 256; ++c) {
        float v = eb[(size_t)c * HW] + pb[(size_t)c * HW];
        qacc = fmaf(wq_w[c], v, qacc);
        float pv = waveRedSum(cntf * v);
        if ((threadIdx.x & 63) == 0) atomicAdd(&ubar[n * 256 + c], pv);
    }
    qdot[n * HW + yx] = qacc + wq_b[0];
}

// --------------------------- PassB: softmax stats, spq, w_eff, b_eff (per n)
__global__ __launch_bounds__(256) void pass_b(
    const float* __restrict__ qdot, const float* __restrict__ ubar_raw,
    const float* __restrict__ sp_wq_w, const float* __restrict__ sp_wq_b,
    const float* __restrict__ sp_wv_w, const float* __restrict__ sp_wv_b,
    float* __restrict__ Mn, float* __restrict__ invZn,
    float* __restrict__ w_eff, float* __restrict__ b_eff,
    int sh, int kh, int win, float invL)
{
    int n = blockIdx.x, tid = threadIdx.x;
    __shared__ float red[256];
    __shared__ float ub[256];
    __shared__ float spq[128];
    // --- max of qdot
    float m = -1e30f;
    for (int p = tid; p < HW; p += 256) m = fmaxf(m, qdot[n * HW + p]);
    red[tid] = m; __syncthreads();
    for (int s = 128; s > 0; s >>= 1) { if (tid < s) red[tid] = fmaxf(red[tid], red[tid + s]); __syncthreads(); }
    float M = red[0]; __syncthreads();
    // --- Z = sum cnt*exp(qdot-M)
    float z = 0.f;
    for (int p = tid; p < HW; p += 256) {
        int y = p >> 6, x = p & 63;
        float cf = (float)(cnt1f(y, sh, kh, win) * cnt1f(x, sh, kh, win));
        z += cf * expf(qdot[n * HW + p] - M);
    }
    red[tid] = z; __syncthreads();
    for (int s = 128; s > 0; s >>= 1) { if (tid < s) red[tid] += red[tid + s]; __syncthreads(); }
    float Z = red[0];
    if (tid == 0) { Mn[n] = M; invZn[n] = 1.f / Z; }
    __syncthreads();
    // --- ubar (scaled), spq logits, softmax over 128
    ub[tid] = ubar_raw[n * 256 + tid] * invL;
    __syncthreads();
    float sl = -1e30f;
    if (tid < 128) {
        float a = sp_wq_b[tid];
        for (int c = 0; c < 256; ++c) a = fmaf(sp_wq_w[tid * 256 + c], ub[c], a);
        sl = a;
    }
    red[tid] = sl; __syncthreads();
    for (int s = 128; s > 0; s >>= 1) { if (tid < s) red[tid] = fmaxf(red[tid], red[tid + s]); __syncthreads(); }
    float m2 = red[0]; __syncthreads();
    float e = (tid < 128) ? expf(sl - m2) : 0.f;
    red[tid] = e; __syncthreads();
    for (int s = 128; s > 0; s >>= 1) { if (tid < s) red[tid] += red[tid + s]; __syncthreads(); }
    float S2 = red[0]; __syncthreads();
    if (tid < 128) spq[tid] = e / S2;
    __syncthreads();
    // --- w_eff[c] = sum_c2 spq[c2]*sp_wv_w[c2,c];  b_eff = spq . sp_wv_b
    float a = 0.f;
    for (int c2 = 0; c2 < 128; ++c2) a = fmaf(spq[c2], sp_wv_w[c2 * 256 + tid], a);
    w_eff[n * 256 + tid] = a;
    if (tid == 0) {
        float bb = 0.f;
        for (int c2 = 0; c2 < 128; ++c2) bb = fmaf(spq[c2], sp_wv_b[c2], bb);
        b_eff[n] = bb;
    }
}

// --------------------------------------- PassC: uq accum + wdot -> spw
__global__ __launch_bounds__(256) void pass_c(
    const float* __restrict__ expx, const float* __restrict__ pos,
    const float* __restrict__ qdot, const float* __restrict__ Mn,
    const float* __restrict__ invZn, const float* __restrict__ w_eff,
    const float* __restrict__ b_eff, float* __restrict__ uq,
    float* __restrict__ spw, int branch, int sh, int kh, int win)
{
    int n = blockIdx.y;
    int yx = blockIdx.x * 256 + threadIdx.x;
    int y = yx >> 6, x = yx & 63;
    float cntf = (float)(cnt1f(y, sh, kh, win) * cnt1f(x, sh, kh, win));
    float wq = expf(qdot[n * HW + yx] - Mn[n]) * invZn[n];
    float t = cntf * wq;
    const float* eb = expx + ((size_t)(n * 768 + branch * 256)) * HW + yx;
    const float* pb = pos + yx;
    const float* we = w_eff + n * 256;
    float wacc = 0.f;
    for (int c = 0; c < 256; ++c) {
        float v = eb[(size_t)c * HW] + pb[(size_t)c * HW];
        wacc = fmaf(we[c], v, wacc);
        float pv = waveRedSum(t * v);
        if ((threadIdx.x & 63) == 0) atomicAdd(&uq[n * 256 + c], pv);
    }
    spw[n * HW + yx] = 1.f / (1.f + expf(-(wacc + b_eff[n])));
}

// --------------------------------------- PassD: z -> wz -> LN -> ch_w (per n)
__global__ __launch_bounds__(256) void pass_d(
    const float* __restrict__ uq,
    const float* __restrict__ ch_wv_w, const float* __restrict__ ch_wv_b,
    const float* __restrict__ ch_wz_w, const float* __restrict__ ch_wz_b,
    const float* __restrict__ ln_g, const float* __restrict__ ln_b,
    float* __restrict__ ch_w)
{
    int n = blockIdx.x, tid = threadIdx.x;
    __shared__ float zz[128];
    __shared__ float red[256];
    __shared__ float uql[256];
    uql[tid] = uq[n * 256 + tid];
    __syncthreads();
    if (tid < 128) {
        float a = ch_wv_b[tid];
        for (int c = 0; c < 256; ++c) a = fmaf(ch_wv_w[tid * 256 + c], uql[c], a);
        zz[tid] = a;
    }
    __syncthreads();
    float wz = ch_wz_b[tid];
    for (int c2 = 0; c2 < 128; ++c2) wz = fmaf(ch_wz_w[tid * 128 + c2], zz[c2], wz);
    red[tid] = wz; __syncthreads();
    for (int s = 128; s > 0; s >>= 1) { if (tid < s) red[tid] += red[tid + s]; __syncthreads(); }
    float mean = red[0] * (1.f / 256.f); __syncthreads();
    float d = wz - mean;
    red[tid] = d * d; __syncthreads();
    for (int s = 128; s > 0; s >>= 1) { if (tid < s) red[tid] += red[tid + s]; __syncthreads(); }
    float var = red[0] * (1.f / 256.f);
    float xn = d / sqrtf(var + 1e-5f);
    ch_w[n * 256 + tid] = 1.f / (1.f + expf(-(xn * ln_g[tid] + ln_b[tid])));
}

// ------------------- PassE: combined = expx + v*(ch_w + spw), in-place
__global__ __launch_bounds__(256) void pass_e(
    float* __restrict__ expx, const float* __restrict__ pos,
    const float* __restrict__ ch_w, const float* __restrict__ spw, int branch)
{
    size_t idx4 = ((size_t)blockIdx.x * 256 + threadIdx.x) * 4;  // < 8*256*4096
    int n = (int)(idx4 >> 20);
    int r = (int)(idx4 & 1048575);
    int c = r >> 12;
    int yx = r & 4095;
    float* ep = expx + (((size_t)(n * 768 + branch * 256 + c)) << 12) + yx;
    const float4 ev = *(const float4*)ep;
    const float4 pv = *(const float4*)(pos + (((size_t)c) << 12) + yx);
    const float4 sv = *(const float4*)(spw + (((size_t)n) << 12) + yx);
    float cw = ch_w[n * 256 + c];
    float4 o;
    o.x = ev.x + (ev.x + pv.x) * (cw + sv.x);
    o.y = ev.y + (ev.y + pv.y) * (cw + sv.y);
    o.z = ev.z + (ev.z + pv.z) * (cw + sv.z);
    o.w = ev.w + (ev.w + pv.w) * (cw + sv.w);
    *(float4*)ep = o;
}

// ---------------------------------------------------------------------------
extern "C" void kernel_launch(void* const* d_in, const int* in_sizes, int n_in,
                              void* d_out, int out_size, void* d_ws, size_t ws_size,
                              hipStream_t stream) {
    const float* x        = (const float*)d_in[0];
    const float* w_exp    = (const float*)d_in[1];
    const float* b_exp    = (const float*)d_in[2];
    const float* w_res    = (const float*)d_in[3];
    const float* b_res    = (const float*)d_in[4];
    const float* w_fus    = (const float*)d_in[5];
    const float* b_fus    = (const float*)d_in[6];
    const float* ch_wv_w  = (const float*)d_in[7];
    const float* ch_wv_b  = (const float*)d_in[8];
    const float* ch_wq_w  = (const float*)d_in[9];
    const float* ch_wq_b  = (const float*)d_in[10];
    const float* ch_wz_w  = (const float*)d_in[11];
    const float* ch_wz_b  = (const float*)d_in[12];
    const float* ln_g     = (const float*)d_in[13];
    const float* ln_b     = (const float*)d_in[14];
    const float* sp_wv_w  = (const float*)d_in[15];
    const float* sp_wv_b  = (const float*)d_in[16];
    const float* sp_wq_w  = (const float*)d_in[17];
    const float* sp_wq_b  = (const float*)d_in[18];
    float* out = (float*)d_out;
    float* ws  = (float*)d_ws;

    float* pos     = ws;                  // 1,048,576
    float* expx    = ws + 1048576;        // 25,165,824  (becomes `combined` in-place)
    float* out_res = ws + 26214400;       // 8,388,608
    float* sm      = ws + 34603008;
    float* ubar3   = sm;                  // 3*8*256 = 6144 (atomic accum, zeroed)
    float* uq3     = sm + 6144;           // 6144 (atomic accum, zeroed)
    float* qdot    = sm + 12288;          // 8*4096
    float* spw     = sm + 45056;          // 8*4096
    float* Mn      = sm + 77824;          // 8
    float* invZn   = sm + 77832;          // 8
    float* beff    = sm + 77840;          // 8
    float* weff    = sm + 77848;          // 8*256
    float* chw     = sm + 79896;          // 8*256

    zero_kernel<<<48, 256, 0, stream>>>(ubar3, 12288);
    pos_kernel<<<4096, 256, 0, stream>>>(pos);
    gemm1x1<false><<<dim3(64, 12, NB), 256, 0, stream>>>(w_exp, b_exp, x, nullptr, expx, 768, 256);

    const int wins[3] = {2, 4, 6};
    for (int i = 0; i < 3; ++i) {
        int win = wins[i];
        int sh = 64 / win;
        int kh = sh + 64 % win;
        float invL = 1.f / (float)(win * win * kh * kh);
        float* ubar = ubar3 + i * 2048;
        float* uqb  = uq3 + i * 2048;
        pass_a<<<dim3(16, NB), 256, 0, stream>>>(expx, pos, ch_wq_w, ch_wq_b, qdot, ubar, i, sh, kh, win);
        pass_b<<<NB, 256, 0, stream>>>(qdot, ubar, sp_wq_w, sp_wq_b, sp_wv_w, sp_wv_b,
                                       Mn, invZn, weff, beff, sh, kh, win, invL);
        pass_c<<<dim3(16, NB), 256, 0, stream>>>(expx, pos, qdot, Mn, invZn, weff, beff,
                                                 uqb, spw, i, sh, kh, win);
        pass_d<<<NB, 256, 0, stream>>>(uqb, ch_wv_w, ch_wv_b, ch_wz_w, ch_wz_b, ln_g, ln_b, chw);
        pass_e<<<8192, 256, 0, stream>>>(expx, pos, chw, spw, i);
    }

    gemm1x1<true><<<dim3(64, 4, NB), 256, 0, stream>>>(w_res, b_res, expx, x, out_res, 256, 768);
    gemm1x1<false><<<dim3(64, 4, NB), 256, 0, stream>>>(w_fus, b_fus, out_res, nullptr, out, 256, 256);
}

// Round 2
// 739.896 us; speedup vs baseline: 2.2553x; 2.2553x over previous
//
#include <hip/hip_runtime.h>
#include <cstddef>

// ---------------------------------------------------------------------------
// PatchAttention, algebraically simplified. All PSA per-pixel quantities are
// linear functionals of x composed with W_exp, so the heavy passes read x
// (32 MB) instead of expx (96 MB) and reductions are block-per-(n,c):
//   expx   = W_exp @ x + b                       (GEMM, kept for pass_e/GEMM2)
//   qdot_i = g_i.x + wq.pos + c0_i               g_i = W_exp_i^T @ ch_wq_w
//   ubar_i = W_exp_i @ xbar_i + posbar_i + b*L   xbar = cnt-weighted sum of x
//   pass_b: cnt-weighted softmax stats, spq, w_eff, b_eff       (per i,n)
//   wdot_i = h_i.x + w_eff.pos + btot            h_i = W_exp_i^T @ w_eff
//   spw    = sigmoid(wdot);  t_i = cnt*softmax(qdot)
//   uq_i   = W_exp_i @ xq_i + posq_i + b         xq = t-weighted sum of x
//   pass_d: z->wz->LN->sigmoid -> ch_w
//   pass_e: combined = expx + (expx+pos)*(ch_w[c]+spw[yx])   (in-place)
//   out    = W_fus@x + bias_comb  +  (W_fus@W_res) @ combined     (2 GEMMs)
// ---------------------------------------------------------------------------

#define HW 4096

__device__ __forceinline__ int cnt1f(int y, int sh, int kh, int win) {
    int t = y - kh + sh;
    int lo = t > 0 ? t / sh : 0;
    int hi = min(win - 1, y / sh);
    return hi - lo + 1;
}

__device__ __forceinline__ float blockReduceSum(float v, float* red) {
    int tid = threadIdx.x;
    red[tid] = v; __syncthreads();
    for (int s = 128; s > 0; s >>= 1) { if (tid < s) red[tid] += red[tid + s]; __syncthreads(); }
    float r = red[0]; __syncthreads();
    return r;
}

// ---------------------------------------------------------------- pos encode
__global__ __launch_bounds__(256) void pos_kernel(float* __restrict__ pos) {
    int idx = blockIdx.x * 256 + threadIdx.x;      // < 1048576
    int row = idx >> 8, col = idx & 255;
    int a = row >> 6, b = row & 63;
    int g = col >> 6, k = col & 63;
    float omega = expf(-(float)k * (9.2103403719761836f / 64.f)); // 10000^(-k/64)
    float arg = (g < 2 ? (float)a : (float)b) * omega;
    pos[idx] = (g & 1) ? cosf(arg) : sinf(arg);
}

// ------------------------------- g_i = W_exp_i^T @ ch_wq_w ; c0_i (grid 3)
__global__ __launch_bounds__(256) void prep_g(
    const float* __restrict__ W_exp, const float* __restrict__ b_exp,
    const float* __restrict__ wq, const float* __restrict__ wq_b,
    float* __restrict__ g, float* __restrict__ c0)
{
    int i = blockIdx.x, tid = threadIdx.x;
    __shared__ float wql[256];
    wql[tid] = wq[tid];
    __syncthreads();
    const float* Wb = W_exp + (size_t)i * 256 * 256;
    float acc = 0.f;
    for (int oc = 0; oc < 256; ++oc) acc = fmaf(wql[oc], Wb[oc * 256 + tid], acc);
    g[i * 256 + tid] = acc;
    if (tid == 0) {
        float b = wq_b[0];
        for (int oc = 0; oc < 256; ++oc) b = fmaf(wql[oc], b_exp[i * 256 + oc], b);
        c0[i] = b;
    }
}

// -------- Wcomb = W_fus @ W_res [256,768]; biasc = W_fus@b_res+b_fus (grid 256)
__global__ __launch_bounds__(256) void prep_wcomb(
    const float* __restrict__ W_fus, const float* __restrict__ W_res,
    const float* __restrict__ b_res, const float* __restrict__ b_fus,
    float* __restrict__ Wcomb, float* __restrict__ biasc)
{
    int o = blockIdx.x, tid = threadIdx.x;
    __shared__ float wrow[256];
    wrow[tid] = W_fus[o * 256 + tid];
    __syncthreads();
    for (int k = 0; k < 3; ++k) {
        int j = tid + k * 256;
        float acc = 0.f;
        for (int c = 0; c < 256; ++c) acc = fmaf(wrow[c], W_res[c * 768 + j], acc);
        Wcomb[o * 768 + j] = acc;
    }
    if (tid == 0) {
        float b = b_fus[o];
        for (int c = 0; c < 256; ++c) b = fmaf(wrow[c], b_res[c], b);
        biasc[o] = b;
    }
}

// ---------------------------------------------------------------- fp32 GEMM
// Out[n,o,p] = sum_c W[o,c] * X[n,c,p] (+ bias[o]) (+ Res[n,o,p])
template<bool ADD_RES, bool ADD_BIAS>
__global__ __launch_bounds__(256) void gemm1x1(
    const float* __restrict__ W, const float* __restrict__ bias,
    const float* __restrict__ X, const float* __restrict__ Res,
    float* __restrict__ Out, int O, int Cin)
{
    const int P = HW;
    __shared__ __align__(16) float As[16][68];
    __shared__ __align__(16) float Bs[16][64];
    int n = blockIdx.z;
    int p0 = blockIdx.x * 64;
    int o0 = blockIdx.y * 64;
    int tid = threadIdx.x;
    int tx = tid & 15, ty = tid >> 4;
    const float* Xn = X + (size_t)n * Cin * P;
    int lm = tid >> 2, lk = (tid & 3) * 4;   // A loader: 64 rows x 16 cols
    int bk = tid >> 4, bp = (tid & 15) * 4;  // B loader: 16 rows x 64 cols
    float acc[4][4] = {};
    for (int k0 = 0; k0 < Cin; k0 += 16) {
        float4 av = *(const float4*)(W + (size_t)(o0 + lm) * Cin + k0 + lk);
        float4 bv = *(const float4*)(Xn + (size_t)(k0 + bk) * P + p0 + bp);
        __syncthreads();
        As[lk + 0][lm] = av.x; As[lk + 1][lm] = av.y;
        As[lk + 2][lm] = av.z; As[lk + 3][lm] = av.w;
        *(float4*)&Bs[bk][bp] = bv;
        __syncthreads();
        #pragma unroll
        for (int k = 0; k < 16; ++k) {
            float4 a = *(const float4*)&As[k][ty * 4];
            float4 b = *(const float4*)&Bs[k][tx * 4];
            float a4[4] = {a.x, a.y, a.z, a.w};
            float b4[4] = {b.x, b.y, b.z, b.w};
            #pragma unroll
            for (int i = 0; i < 4; ++i)
                #pragma unroll
                for (int j = 0; j < 4; ++j)
                    acc[i][j] = fmaf(a4[i], b4[j], acc[i][j]);
        }
    }
    #pragma unroll
    for (int i = 0; i < 4; ++i) {
        int o = o0 + ty * 4 + i;
        float bo = ADD_BIAS ? bias[o] : 0.f;
        float4 r;
        r.x = acc[i][0] + bo; r.y = acc[i][1] + bo;
        r.z = acc[i][2] + bo; r.w = acc[i][3] + bo;
        size_t off = ((size_t)n * O + o) * P + p0 + tx * 4;
        if (ADD_RES) {
            float4 rv = *(const float4*)(Res + off);
            r.x += rv.x; r.y += rv.y; r.z += rv.z; r.w += rv.w;
        }
        *(float4*)(Out + off) = r;
    }
}

// ------------- xbar (cnt-weighted sums of x rows) + posbar (grid 256 x 9)
__global__ __launch_bounds__(256) void xbar_kernel(
    const float* __restrict__ x, const float* __restrict__ pos,
    float* __restrict__ xbar_all, float* __restrict__ xbar6,
    float* __restrict__ posbar, float* __restrict__ posbar6)
{
    int c = blockIdx.x, n = blockIdx.y, tid = threadIdx.x;
    const float* src = (n < 8) ? x + (((size_t)(n * 256 + c)) << 12)
                               : pos + (((size_t)c) << 12);
    float sa = 0.f, s6 = 0.f;
    #pragma unroll
    for (int k = 0; k < 4; ++k) {
        int f4 = tid + k * 256;
        float4 v = *(const float4*)(src + f4 * 4);
        int p = f4 * 4;
        int y = p >> 6, xx = p & 63;
        float cy = (float)cnt1f(y, 10, 14, 6);
        float c0_ = cy * (float)cnt1f(xx + 0, 10, 14, 6);
        float c1_ = cy * (float)cnt1f(xx + 1, 10, 14, 6);
        float c2_ = cy * (float)cnt1f(xx + 2, 10, 14, 6);
        float c3_ = cy * (float)cnt1f(xx + 3, 10, 14, 6);
        sa += v.x + v.y + v.z + v.w;
        s6 += c0_ * v.x + c1_ * v.y + c2_ * v.z + c3_ * v.w;
    }
    __shared__ float red[256];
    float ra = blockReduceSum(sa, red);
    float r6 = blockReduceSum(s6, red);
    if (tid == 0) {
        if (n < 8) { xbar_all[n * 256 + c] = ra; xbar6[n * 256 + c] = r6; }
        else       { posbar[c] = ra;             posbar6[c] = r6; }
    }
}

// --------------------------- qdot_i[n,p] = g_i.x + wq.pos + c0_i (grid 16x8)
__global__ __launch_bounds__(256) void qdot_kernel(
    const float* __restrict__ x, const float* __restrict__ pos,
    const float* __restrict__ g, const float* __restrict__ c0,
    const float* __restrict__ wq, float* __restrict__ qdot)
{
    int n = blockIdx.y, tid = threadIdx.x;
    int p = blockIdx.x * 256 + tid;
    __shared__ float gl[768];
    __shared__ float wql[256];
    gl[tid] = g[tid]; gl[256 + tid] = g[256 + tid]; gl[512 + tid] = g[512 + tid];
    wql[tid] = wq[tid];
    __syncthreads();
    const float* xp = x + (((size_t)n) << 20) + p;
    const float* pp = pos + p;
    float q0 = 0.f, q1 = 0.f, q2 = 0.f, qp = 0.f;
    #pragma unroll 4
    for (int c = 0; c < 256; ++c) {
        float xv = xp[(size_t)c << 12];
        float pv = pp[(size_t)c << 12];
        q0 = fmaf(gl[c], xv, q0);
        q1 = fmaf(gl[256 + c], xv, q1);
        q2 = fmaf(gl[512 + c], xv, q2);
        qp = fmaf(wql[c], pv, qp);
    }
    qdot[((0 * 8 + n) << 12) + p] = q0 + qp + c0[0];
    qdot[((1 * 8 + n) << 12) + p] = q1 + qp + c0[1];
    qdot[((2 * 8 + n) << 12) + p] = q2 + qp + c0[2];
}

// ------------- ubar_i[n,c] = W_exp_i[c,:]@xbar_i + b*L_i + posbar_i (grid 3x8)
__global__ __launch_bounds__(256) void ubar_mv(
    const float* __restrict__ W_exp, const float* __restrict__ b_exp,
    const float* __restrict__ xbar_all, const float* __restrict__ xbar6,
    const float* __restrict__ posbar, const float* __restrict__ posbar6,
    float* __restrict__ ubar)
{
    int i = blockIdx.x, n = blockIdx.y, tid = threadIdx.x;
    __shared__ float xb[256];
    const float* xsrc = (i < 2) ? xbar_all : xbar6;
    xb[tid] = xsrc[n * 256 + tid];
    __syncthreads();
    int win = 2 * (i + 1), sh = 64 / win, kh = sh + 64 % win;
    float Li = (float)(win * win * kh * kh);
    const float* pb = (i < 2) ? posbar : posbar6;
    float acc = b_exp[i * 256 + tid] * Li + pb[tid];
    const float* Wr = W_exp + ((size_t)(i * 256 + tid)) * 256;
    for (int cin = 0; cin < 256; ++cin) acc = fmaf(Wr[cin], xb[cin], acc);
    ubar[(i * 8 + n) * 256 + tid] = acc;
}

// --------------------------- softmax stats, spq, w_eff, b_eff (grid 3x8)
__global__ __launch_bounds__(256) void pass_b(
    const float* __restrict__ qdot, const float* __restrict__ ubar_raw,
    const float* __restrict__ sp_wq_w, const float* __restrict__ sp_wq_b,
    const float* __restrict__ sp_wv_w, const float* __restrict__ sp_wv_b,
    float* __restrict__ Mn, float* __restrict__ invZn,
    float* __restrict__ w_eff, float* __restrict__ b_eff)
{
    int i = blockIdx.x, n = blockIdx.y, tid = threadIdx.x;
    int b = i * 8 + n;
    int win = 2 * (i + 1), sh = 64 / win, kh = sh + 64 % win;
    float invL = 1.f / (float)(win * win * kh * kh);
    const float* qd = qdot + (((size_t)b) << 12);
    __shared__ float red[256];
    __shared__ float ub[256];
    __shared__ float spq[128];
    float m = -1e30f;
    for (int p = tid; p < HW; p += 256) m = fmaxf(m, qd[p]);
    red[tid] = m; __syncthreads();
    for (int s = 128; s > 0; s >>= 1) { if (tid < s) red[tid] = fmaxf(red[tid], red[tid + s]); __syncthreads(); }
    float M = red[0]; __syncthreads();
    float z = 0.f;
    for (int p = tid; p < HW; p += 256) {
        int y = p >> 6, xx = p & 63;
        float cf = (float)(cnt1f(y, sh, kh, win) * cnt1f(xx, sh, kh, win));
        z += cf * expf(qd[p] - M);
    }
    red[tid] = z; __syncthreads();
    for (int s = 128; s > 0; s >>= 1) { if (tid < s) red[tid] += red[tid + s]; __syncthreads(); }
    float Z = red[0]; __syncthreads();
    if (tid == 0) { Mn[b] = M; invZn[b] = 1.f / Z; }
    ub[tid] = ubar_raw[b * 256 + tid] * invL;
    __syncthreads();
    float sl = -1e30f;
    if (tid < 128) {
        float a = sp_wq_b[tid];
        for (int c = 0; c < 256; ++c) a = fmaf(sp_wq_w[tid * 256 + c], ub[c], a);
        sl = a;
    }
    red[tid] = sl; __syncthreads();
    for (int s = 128; s > 0; s >>= 1) { if (tid < s) red[tid] = fmaxf(red[tid], red[tid + s]); __syncthreads(); }
    float m2 = red[0]; __syncthreads();
    float e = (tid < 128) ? expf(sl - m2) : 0.f;
    red[tid] = e; __syncthreads();
    for (int s = 128; s > 0; s >>= 1) { if (tid < s) red[tid] += red[tid + s]; __syncthreads(); }
    float S2 = red[0]; __syncthreads();
    if (tid < 128) spq[tid] = e / S2;
    __syncthreads();
    float a = 0.f;
    for (int c2 = 0; c2 < 128; ++c2) a = fmaf(spq[c2], sp_wv_w[c2 * 256 + tid], a);
    w_eff[b * 256 + tid] = a;
    if (tid == 0) {
        float bb = 0.f;
        for (int c2 = 0; c2 < 128; ++c2) bb = fmaf(spq[c2], sp_wv_b[c2], bb);
        b_eff[b] = bb;
    }
}

// ------------- h_i[n,:] = W_exp_i^T @ w_eff ; btot = b_eff + w_eff.b (grid 3x8)
__global__ __launch_bounds__(256) void h_kernel(
    const float* __restrict__ W_exp, const float* __restrict__ b_exp,
    const float* __restrict__ weff, const float* __restrict__ beff,
    float* __restrict__ h, float* __restrict__ btot)
{
    int i = blockIdx.x, n = blockIdx.y, tid = threadIdx.x;
    int b = i * 8 + n;
    __shared__ float we[256];
    we[tid] = weff[b * 256 + tid];
    __syncthreads();
    const float* Wb = W_exp + (size_t)i * 256 * 256;
    float acc = 0.f;
    for (int oc = 0; oc < 256; ++oc) acc = fmaf(we[oc], Wb[oc * 256 + tid], acc);
    h[b * 256 + tid] = acc;
    if (tid == 0) {
        float bb = beff[b];
        for (int oc = 0; oc < 256; ++oc) bb = fmaf(we[oc], b_exp[i * 256 + oc], bb);
        btot[b] = bb;
    }
}

// --------- spw_i = sigmoid(h_i.x + w_eff.pos + btot); t_i = cnt*softmax (16x8)
__global__ __launch_bounds__(256) void spw_t_kernel(
    const float* __restrict__ x, const float* __restrict__ pos,
    const float* __restrict__ h, const float* __restrict__ weff,
    const float* __restrict__ qdot, const float* __restrict__ Mn,
    const float* __restrict__ invZn, const float* __restrict__ btot,
    float* __restrict__ spw, float* __restrict__ tbuf)
{
    int n = blockIdx.y, tid = threadIdx.x;
    int p = blockIdx.x * 256 + tid;
    __shared__ float hl[768], wl[768];
    #pragma unroll
    for (int i = 0; i < 3; ++i) {
        hl[i * 256 + tid] = h[(i * 8 + n) * 256 + tid];
        wl[i * 256 + tid] = weff[(i * 8 + n) * 256 + tid];
    }
    __syncthreads();
    const float* xp = x + (((size_t)n) << 20) + p;
    const float* pp = pos + p;
    float a0 = 0.f, a1 = 0.f, a2 = 0.f;
    #pragma unroll 4
    for (int c = 0; c < 256; ++c) {
        float xv = xp[(size_t)c << 12];
        float pv = pp[(size_t)c << 12];
        a0 += hl[c] * xv + wl[c] * pv;
        a1 += hl[256 + c] * xv + wl[256 + c] * pv;
        a2 += hl[512 + c] * xv + wl[512 + c] * pv;
    }
    int y = p >> 6, xx = p & 63;
    float a[3] = {a0, a1, a2};
    #pragma unroll
    for (int i = 0; i < 3; ++i) {
        int b = i * 8 + n;
        int win = 2 * (i + 1), sh = 64 / win, kh = sh + 64 % win;
        float cf = (float)(cnt1f(y, sh, kh, win) * cnt1f(xx, sh, kh, win));
        int idx = (b << 12) + p;
        spw[idx] = 1.f / (1.f + expf(-(a[i] + btot[b])));
        tbuf[idx] = cf * expf(qdot[idx] - Mn[b]) * invZn[b];
    }
}

// ------------- xq_i[n,c] = sum t_i*x ; posq_i[n,c] = sum t_i*pos (grid 256x8)
__global__ __launch_bounds__(256) void xq_kernel(
    const float* __restrict__ x, const float* __restrict__ pos,
    const float* __restrict__ tbuf, float* __restrict__ xq, float* __restrict__ posq)
{
    int c = blockIdx.x, n = blockIdx.y, tid = threadIdx.x;
    const float* xr = x + (((size_t)(n * 256 + c)) << 12);
    const float* pr = pos + (((size_t)c) << 12);
    float ax[3] = {0.f, 0.f, 0.f}, ap[3] = {0.f, 0.f, 0.f};
    #pragma unroll
    for (int k = 0; k < 4; ++k) {
        int f4 = tid + k * 256;
        float4 xv = *(const float4*)(xr + f4 * 4);
        float4 pv = *(const float4*)(pr + f4 * 4);
        #pragma unroll
        for (int i = 0; i < 3; ++i) {
            float4 tv = *(const float4*)(tbuf + (((size_t)(i * 8 + n)) << 12) + f4 * 4);
            ax[i] += tv.x * xv.x + tv.y * xv.y + tv.z * xv.z + tv.w * xv.w;
            ap[i] += tv.x * pv.x + tv.y * pv.y + tv.z * pv.z + tv.w * pv.w;
        }
    }
    __shared__ float red[256];
    #pragma unroll
    for (int i = 0; i < 3; ++i) {
        float rx = blockReduceSum(ax[i], red);
        float rp = blockReduceSum(ap[i], red);
        if (tid == 0) { xq[(i * 8 + n) * 256 + c] = rx; posq[(i * 8 + n) * 256 + c] = rp; }
    }
}

// ------------- uq_i[n,c] = W_exp_i[c,:]@xq_i + b + posq_i (grid 3x8)
__global__ __launch_bounds__(256) void uq_mv(
    const float* __restrict__ W_exp, const float* __restrict__ b_exp,
    const float* __restrict__ xq, const float* __restrict__ posq,
    float* __restrict__ uq)
{
    int i = blockIdx.x, n = blockIdx.y, tid = threadIdx.x;
    int b = i * 8 + n;
    __shared__ float xb[256];
    xb[tid] = xq[b * 256 + tid];
    __syncthreads();
    float acc = b_exp[i * 256 + tid] + posq[b * 256 + tid];
    const float* Wr = W_exp + ((size_t)(i * 256 + tid)) * 256;
    for (int cin = 0; cin < 256; ++cin) acc = fmaf(Wr[cin], xb[cin], acc);
    uq[b * 256 + tid] = acc;
}

// --------------------------------------- z -> wz -> LN -> ch_w (grid 3x8)
__global__ __launch_bounds__(256) void pass_d(
    const float* __restrict__ uq,
    const float* __restrict__ ch_wv_w, const float* __restrict__ ch_wv_b,
    const float* __restrict__ ch_wz_w, const float* __restrict__ ch_wz_b,
    const float* __restrict__ ln_g, const float* __restrict__ ln_b,
    float* __restrict__ ch_w)
{
    int i = blockIdx.x, n = blockIdx.y, tid = threadIdx.x;
    int b = i * 8 + n;
    __shared__ float zz[128];
    __shared__ float red[256];
    __shared__ float uql[256];
    uql[tid] = uq[b * 256 + tid];
    __syncthreads();
    if (tid < 128) {
        float a = ch_wv_b[tid];
        for (int c = 0; c < 256; ++c) a = fmaf(ch_wv_w[tid * 256 + c], uql[c], a);
        zz[tid] = a;
    }
    __syncthreads();
    float wz = ch_wz_b[tid];
    for (int c2 = 0; c2 < 128; ++c2) wz = fmaf(ch_wz_w[tid * 128 + c2], zz[c2], wz);
    red[tid] = wz; __syncthreads();
    for (int s = 128; s > 0; s >>= 1) { if (tid < s) red[tid] += red[tid + s]; __syncthreads(); }
    float mean = red[0] * (1.f / 256.f); __syncthreads();
    float d = wz - mean;
    red[tid] = d * d; __syncthreads();
    for (int s = 128; s > 0; s >>= 1) { if (tid < s) red[tid] += red[tid + s]; __syncthreads(); }
    float var = red[0] * (1.f / 256.f);
    float xn = d / sqrtf(var + 1e-5f);
    ch_w[b * 256 + tid] = 1.f / (1.f + expf(-(xn * ln_g[tid] + ln_b[tid])));
}

// ------------- combined = expx + (expx+pos)*(ch_w+spw), in-place (3072x8)
__global__ __launch_bounds__(256) void pass_e(
    float* __restrict__ expx, const float* __restrict__ pos,
    const float* __restrict__ chw, const float* __restrict__ spw)
{
    int n = blockIdx.y;
    int r4 = blockIdx.x * 256 + threadIdx.x;     // float4 idx within n (768*1024)
    int c768 = r4 >> 10;
    int yx = (r4 & 1023) * 4;
    int i = c768 >> 8, c = c768 & 255;
    float* ep = expx + (((size_t)(n * 768 + c768)) << 12) + yx;
    const float4 ev = *(const float4*)ep;
    const float4 pv = *(const float4*)(pos + (((size_t)c) << 12) + yx);
    const float4 sv = *(const float4*)(spw + (((size_t)(i * 8 + n)) << 12) + yx);
    float cw = chw[(i * 8 + n) * 256 + c];
    float4 o;
    o.x = ev.x + (ev.x + pv.x) * (cw + sv.x);
    o.y = ev.y + (ev.y + pv.y) * (cw + sv.y);
    o.z = ev.z + (ev.z + pv.z) * (cw + sv.z);
    o.w = ev.w + (ev.w + pv.w) * (cw + sv.w);
    *(float4*)ep = o;
}

// ---------------------------------------------------------------------------
extern "C" void kernel_launch(void* const* d_in, const int* in_sizes, int n_in,
                              void* d_out, int out_size, void* d_ws, size_t ws_size,
                              hipStream_t stream) {
    const float* x        = (const float*)d_in[0];
    const float* w_exp    = (const float*)d_in[1];
    const float* b_exp    = (const float*)d_in[2];
    const float* w_res    = (const float*)d_in[3];
    const float* b_res    = (const float*)d_in[4];
    const float* w_fus    = (const float*)d_in[5];
    const float* b_fus    = (const float*)d_in[6];
    const float* ch_wv_w  = (const float*)d_in[7];
    const float* ch_wv_b  = (const float*)d_in[8];
    const float* ch_wq_w  = (const float*)d_in[9];
    const float* ch_wq_b  = (const float*)d_in[10];
    const float* ch_wz_w  = (const float*)d_in[11];
    const float* ch_wz_b  = (const float*)d_in[12];
    const float* ln_g     = (const float*)d_in[13];
    const float* ln_b     = (const float*)d_in[14];
    const float* sp_wv_w  = (const float*)d_in[15];
    const float* sp_wv_b  = (const float*)d_in[16];
    const float* sp_wq_w  = (const float*)d_in[17];
    const float* sp_wq_b  = (const float*)d_in[18];
    float* out = (float*)d_out;
    float* ws  = (float*)d_ws;

    // workspace layout (float offsets); total ~26.76M floats = 107 MB
    float* pos   = ws + 0;          // 1048576
    float* expx  = ws + 1048576;    // 25165824 (becomes `combined` in-place)
    float* qdot  = ws + 26214400;   // 3*8*4096
    float* tbuf  = ws + 26312704;   // 3*8*4096
    float* spw   = ws + 26411008;   // 3*8*4096
    float* g     = ws + 26509312;   // 768
    float* c0    = ws + 26510080;   // 4
    float* xba   = ws + 26510084;   // 2048
    float* xb6   = ws + 26512132;   // 2048
    float* pba   = ws + 26514180;   // 256
    float* pb6   = ws + 26514436;   // 256
    float* ubar  = ws + 26514692;   // 6144
    float* Mn    = ws + 26520836;   // 24
    float* iZ    = ws + 26520860;   // 24
    float* weff  = ws + 26520884;   // 6144
    float* beff  = ws + 26527028;   // 24
    float* btot  = ws + 26527052;   // 24
    float* hb    = ws + 26527076;   // 6144
    float* xq    = ws + 26533220;   // 6144
    float* posq  = ws + 26539364;   // 6144
    float* uq    = ws + 26545508;   // 6144
    float* chw   = ws + 26551652;   // 6144
    float* Wcomb = ws + 26557796;   // 196608
    float* biasc = ws + 26754404;   // 256

    pos_kernel<<<4096, 256, 0, stream>>>(pos);
    prep_g<<<3, 256, 0, stream>>>(w_exp, b_exp, ch_wq_w, ch_wq_b, g, c0);
    prep_wcomb<<<256, 256, 0, stream>>>(w_fus, w_res, b_res, b_fus, Wcomb, biasc);
    gemm1x1<false, true><<<dim3(64, 12, 8), 256, 0, stream>>>(
        w_exp, b_exp, x, nullptr, expx, 768, 256);
    // out = W_fus @ x + bias_comb  (independent of everything above)
    gemm1x1<false, true><<<dim3(64, 4, 8), 256, 0, stream>>>(
        w_fus, biasc, x, nullptr, out, 256, 256);

    xbar_kernel<<<dim3(256, 9), 256, 0, stream>>>(x, pos, xba, xb6, pba, pb6);
    qdot_kernel<<<dim3(16, 8), 256, 0, stream>>>(x, pos, g, c0, ch_wq_w, qdot);
    ubar_mv<<<dim3(3, 8), 256, 0, stream>>>(w_exp, b_exp, xba, xb6, pba, pb6, ubar);
    pass_b<<<dim3(3, 8), 256, 0, stream>>>(qdot, ubar, sp_wq_w, sp_wq_b,
                                           sp_wv_w, sp_wv_b, Mn, iZ, weff, beff);
    h_kernel<<<dim3(3, 8), 256, 0, stream>>>(w_exp, b_exp, weff, beff, hb, btot);
    spw_t_kernel<<<dim3(16, 8), 256, 0, stream>>>(x, pos, hb, weff, qdot, Mn, iZ,
                                                  btot, spw, tbuf);
    xq_kernel<<<dim3(256, 8), 256, 0, stream>>>(x, pos, tbuf, xq, posq);
    uq_mv<<<dim3(3, 8), 256, 0, stream>>>(w_exp, b_exp, xq, posq, uq);
    pass_d<<<dim3(3, 8), 256, 0, stream>>>(uq, ch_wv_w, ch_wv_b, ch_wz_w, ch_wz_b,
                                           ln_g, ln_b, chw);
    pass_e<<<dim3(3072, 8), 256, 0, stream>>>(expx, pos, chw, spw);
    // out += (W_fus@W_res) @ combined
    gemm1x1<true, false><<<dim3(64, 4, 8), 256, 0, stream>>>(
        Wcomb, nullptr, expx, out, out, 256, 768);
}

// Round 3
// 393.726 us; speedup vs baseline: 4.2382x; 1.8792x over previous
//
#include <hip/hip_runtime.h>
#include <cstddef>

// ---------------------------------------------------------------------------
// PatchAttention, algebraically simplified + bf16 MFMA GEMMs.
//   xbT    = bf16(x) transposed to [n][p][c]        (B^T layout for MFMA)
//   expxT  = W_exp @ x + b, stored bf16 [n][p][768] (MFMA GEMM, transposed C)
//   PSA weights chw[i,n,c], spw[i,n,p] computed by fp32 passes on x directly
//   combT  = expxT + (expxT+posT)*(chw+spw)         (in-place, bf16)
//   out    = [W_fus | W_fus@W_res] @ [x ; combined] + biasc   (one MFMA GEMM)
// ---------------------------------------------------------------------------

#define HW 4096
typedef unsigned short ushort_t;
typedef __attribute__((ext_vector_type(8))) short bf16x8;
typedef __attribute__((ext_vector_type(4))) float floatx4;
typedef __attribute__((ext_vector_type(8))) unsigned short ushort8v;

__device__ __forceinline__ ushort_t f2bf(float f) {
    unsigned u = __float_as_uint(f);
    u += 0x7FFF + ((u >> 16) & 1);           // RNE
    return (ushort_t)(u >> 16);
}
__device__ __forceinline__ float bf2f(ushort_t h) {
    return __uint_as_float(((unsigned)h) << 16);
}

__device__ __forceinline__ int cnt1f(int y, int sh, int kh, int win) {
    int t = y - kh + sh;
    int lo = t > 0 ? t / sh : 0;
    int hi = min(win - 1, y / sh);
    return hi - lo + 1;
}

__device__ __forceinline__ float blockReduceSum(float v, float* red) {
    int tid = threadIdx.x;
    red[tid] = v; __syncthreads();
    for (int s = 128; s > 0; s >>= 1) { if (tid < s) red[tid] += red[tid + s]; __syncthreads(); }
    float r = red[0]; __syncthreads();
    return r;
}

// ---------------------------------------------------------------- pos encode
__global__ __launch_bounds__(256) void pos_kernel(float* __restrict__ pos) {
    int idx = blockIdx.x * 256 + threadIdx.x;      // < 1048576
    int row = idx >> 8, col = idx & 255;
    int a = row >> 6, b = row & 63;
    int g = col >> 6, k = col & 63;
    float omega = expf(-(float)k * (9.2103403719761836f / 64.f)); // 10000^(-k/64)
    float arg = (g < 2 ? (float)a : (float)b) * omega;
    pos[idx] = (g & 1) ? cosf(arg) : sinf(arg);
}

// posT[p][c] = pos_chw[c][p], fp32
__global__ __launch_bounds__(256) void posT_kernel(float* __restrict__ posT) {
    int idx = blockIdx.x * 256 + threadIdx.x;      // < 1048576
    int p = idx >> 8, c = idx & 255;
    int f = c * 4096 + p;
    int row = f >> 8, col = f & 255;
    int a = row >> 6, b = row & 63;
    int g = col >> 6, k = col & 63;
    float omega = expf(-(float)k * (9.2103403719761836f / 64.f));
    float arg = (g < 2 ? (float)a : (float)b) * omega;
    posT[idx] = (g & 1) ? cosf(arg) : sinf(arg);
}

// ----------------------- x [n][c][p] fp32 -> xbT [n][p][c] bf16 (32x32 tiles)
__global__ __launch_bounds__(256) void trans_x(
    const float* __restrict__ x, ushort_t* __restrict__ xbT)
{
    __shared__ float L[32][37];
    int n = blockIdx.z;
    int p0 = blockIdx.x * 32, c0 = blockIdx.y * 32;
    int t = threadIdx.x;
    int cc = t >> 3, p4 = (t & 7) * 4;
    const float* src = x + (((size_t)(n * 256 + c0 + cc)) << 12) + p0 + p4;
    float4 v = *(const float4*)src;
    L[cc][p4] = v.x; L[cc][p4 + 1] = v.y; L[cc][p4 + 2] = v.z; L[cc][p4 + 3] = v.w;
    __syncthreads();
    int pp = t >> 3, c4 = (t & 7) * 4;
    unsigned lo = (unsigned)f2bf(L[c4][pp]) | ((unsigned)f2bf(L[c4 + 1][pp]) << 16);
    unsigned hi = (unsigned)f2bf(L[c4 + 2][pp]) | ((unsigned)f2bf(L[c4 + 3][pp]) << 16);
    *(uint2*)&xbT[(((size_t)(n << 12)) + p0 + pp) * 256 + c0 + c4] = make_uint2(lo, hi);
}

// ---------------------------------------------- fp32 -> bf16 (weights)
__global__ __launch_bounds__(256) void conv_bf16(
    const float* __restrict__ src, ushort_t* __restrict__ dst, int nelem)
{
    int i = blockIdx.x * 256 + threadIdx.x;
    if (i < nelem) dst[i] = f2bf(src[i]);
}

// ------------------------------- g_i = W_exp_i^T @ ch_wq_w ; c0_i (grid 3)
__global__ __launch_bounds__(256) void prep_g(
    const float* __restrict__ W_exp, const float* __restrict__ b_exp,
    const float* __restrict__ wq, const float* __restrict__ wq_b,
    float* __restrict__ g, float* __restrict__ c0)
{
    int i = blockIdx.x, tid = threadIdx.x;
    __shared__ float wql[256];
    wql[tid] = wq[tid];
    __syncthreads();
    const float* Wb = W_exp + (size_t)i * 256 * 256;
    float acc = 0.f;
    for (int oc = 0; oc < 256; ++oc) acc = fmaf(wql[oc], Wb[oc * 256 + tid], acc);
    g[i * 256 + tid] = acc;
    if (tid == 0) {
        float b = wq_b[0];
        for (int oc = 0; oc < 256; ++oc) b = fmaf(wql[oc], b_exp[i * 256 + oc], b);
        c0[i] = b;
    }
}

// --- Wcat[o][0:256]=bf16(W_fus), Wcat[o][256:1024]=bf16(W_fus@W_res) (grid 256)
__global__ __launch_bounds__(256) void prep_wcomb(
    const float* __restrict__ W_fus, const float* __restrict__ W_res,
    const float* __restrict__ b_res, const float* __restrict__ b_fus,
    ushort_t* __restrict__ Wcat, float* __restrict__ biasc)
{
    int o = blockIdx.x, tid = threadIdx.x;
    __shared__ float wrow[256];
    wrow[tid] = W_fus[o * 256 + tid];
    __syncthreads();
    Wcat[o * 1024 + tid] = f2bf(wrow[tid]);
    for (int kk = 0; kk < 3; ++kk) {
        int j = tid + kk * 256;
        float acc = 0.f;
        for (int c = 0; c < 256; ++c) acc = fmaf(wrow[c], W_res[c * 768 + j], acc);
        Wcat[o * 1024 + 256 + j] = f2bf(acc);
    }
    if (tid == 0) {
        float b = b_fus[o];
        for (int c = 0; c < 256; ++c) b = fmaf(wrow[c], b_res[c], b);
        biasc[o] = b;
    }
}

// ------------------- MFMA GEMM 1: expxT = W_exp @ x + b, bf16 [n][p][768]
// A = Wb [768][256] bf16, B^T = xbT [n*4096][256] bf16
__global__ __launch_bounds__(256) void gemm_expT(
    const ushort_t* __restrict__ Wb, const ushort_t* __restrict__ XT,
    const float* __restrict__ bias, ushort_t* __restrict__ OutT)
{
    __shared__ ushort_t As[128 * 40];
    __shared__ ushort_t Bs[128 * 40];
    int n = blockIdx.z;
    int p0 = blockIdx.x * 128;
    int o0 = blockIdx.y * 128;
    int t = threadIdx.x;
    int lane = t & 63, wave = t >> 6;
    int wm = (wave & 1) * 64, wn = (wave >> 1) * 64;
    int lr = lane & 15, lk = (lane >> 4) * 8;
    int ar = t >> 2, ac = (t & 3) * 8;
    const ushort_t* A0 = Wb + (size_t)(o0 + ar) * 256 + ac;
    const ushort_t* A1 = Wb + (size_t)(o0 + ar + 64) * 256 + ac;
    const ushort_t* B0 = XT + (((size_t)(n << 12)) + p0 + ar) * 256 + ac;
    const ushort_t* B1 = XT + (((size_t)(n << 12)) + p0 + ar + 64) * 256 + ac;
    floatx4 acc[4][4] = {};
    for (int k0 = 0; k0 < 256; k0 += 32) {
        uint4 a0 = *(const uint4*)(A0 + k0);
        uint4 a1 = *(const uint4*)(A1 + k0);
        uint4 b0 = *(const uint4*)(B0 + k0);
        uint4 b1 = *(const uint4*)(B1 + k0);
        __syncthreads();
        *(uint4*)&As[ar * 40 + ac] = a0;
        *(uint4*)&As[(ar + 64) * 40 + ac] = a1;
        *(uint4*)&Bs[ar * 40 + ac] = b0;
        *(uint4*)&Bs[(ar + 64) * 40 + ac] = b1;
        __syncthreads();
        bf16x8 af[4], bfr[4];
        #pragma unroll
        for (int mi = 0; mi < 4; ++mi)
            af[mi] = *(const bf16x8*)&As[(wm + mi * 16 + lr) * 40 + lk];
        #pragma unroll
        for (int ni = 0; ni < 4; ++ni)
            bfr[ni] = *(const bf16x8*)&Bs[(wn + ni * 16 + lr) * 40 + lk];
        #pragma unroll
        for (int mi = 0; mi < 4; ++mi)
            #pragma unroll
            for (int ni = 0; ni < 4; ++ni)
                acc[mi][ni] = __builtin_amdgcn_mfma_f32_16x16x32_bf16(
                    af[mi], bfr[ni], acc[mi][ni], 0, 0, 0);
    }
    int col = lane & 15, rb = (lane >> 4) * 4;
    #pragma unroll
    for (int mi = 0; mi < 4; ++mi) {
        int o = o0 + wm + mi * 16 + rb;
        float4 bo = *(const float4*)&bias[o];
        #pragma unroll
        for (int ni = 0; ni < 4; ++ni) {
            int p = p0 + wn + ni * 16 + col;
            floatx4 v = acc[mi][ni];
            unsigned lo = (unsigned)f2bf(v[0] + bo.x) | ((unsigned)f2bf(v[1] + bo.y) << 16);
            unsigned hi = (unsigned)f2bf(v[2] + bo.z) | ((unsigned)f2bf(v[3] + bo.w) << 16);
            *(uint2*)&OutT[(((size_t)(n << 12)) + p) * 768 + o] = make_uint2(lo, hi);
        }
    }
}

// ---- MFMA GEMM 2: out = Wcat @ [x ; combined] + biasc, fp32 [n][256][4096]
__global__ __launch_bounds__(256) void gemm_out(
    const ushort_t* __restrict__ Wcat, const ushort_t* __restrict__ XT,
    const ushort_t* __restrict__ CT, const float* __restrict__ biasc,
    float* __restrict__ Out)
{
    __shared__ ushort_t As[128 * 40];
    __shared__ ushort_t Bs[128 * 40];
    int n = blockIdx.z;
    int p0 = blockIdx.x * 128;
    int o0 = blockIdx.y * 128;
    int t = threadIdx.x;
    int lane = t & 63, wave = t >> 6;
    int wm = (wave & 1) * 64, wn = (wave >> 1) * 64;
    int lr = lane & 15, lk = (lane >> 4) * 8;
    int ar = t >> 2, ac = (t & 3) * 8;
    const ushort_t* A0 = Wcat + (size_t)(o0 + ar) * 1024 + ac;
    const ushort_t* A1 = Wcat + (size_t)(o0 + ar + 64) * 1024 + ac;
    const ushort_t* BX0 = XT + (((size_t)(n << 12)) + p0 + ar) * 256 + ac;
    const ushort_t* BX1 = XT + (((size_t)(n << 12)) + p0 + ar + 64) * 256 + ac;
    const ushort_t* BC0 = CT + (((size_t)(n << 12)) + p0 + ar) * 768 + ac;
    const ushort_t* BC1 = CT + (((size_t)(n << 12)) + p0 + ar + 64) * 768 + ac;
    floatx4 acc[4][4] = {};
    for (int k0 = 0; k0 < 1024; k0 += 32) {
        const ushort_t* pb0 = (k0 < 256) ? (BX0 + k0) : (BC0 + (k0 - 256));
        const ushort_t* pb1 = (k0 < 256) ? (BX1 + k0) : (BC1 + (k0 - 256));
        uint4 a0 = *(const uint4*)(A0 + k0);
        uint4 a1 = *(const uint4*)(A1 + k0);
        uint4 b0 = *(const uint4*)pb0;
        uint4 b1 = *(const uint4*)pb1;
        __syncthreads();
        *(uint4*)&As[ar * 40 + ac] = a0;
        *(uint4*)&As[(ar + 64) * 40 + ac] = a1;
        *(uint4*)&Bs[ar * 40 + ac] = b0;
        *(uint4*)&Bs[(ar + 64) * 40 + ac] = b1;
        __syncthreads();
        bf16x8 af[4], bfr[4];
        #pragma unroll
        for (int mi = 0; mi < 4; ++mi)
            af[mi] = *(const bf16x8*)&As[(wm + mi * 16 + lr) * 40 + lk];
        #pragma unroll
        for (int ni = 0; ni < 4; ++ni)
            bfr[ni] = *(const bf16x8*)&Bs[(wn + ni * 16 + lr) * 40 + lk];
        #pragma unroll
        for (int mi = 0; mi < 4; ++mi)
            #pragma unroll
            for (int ni = 0; ni < 4; ++ni)
                acc[mi][ni] = __builtin_amdgcn_mfma_f32_16x16x32_bf16(
                    af[mi], bfr[ni], acc[mi][ni], 0, 0, 0);
    }
    int col = lane & 15, rb = (lane >> 4) * 4;
    #pragma unroll
    for (int mi = 0; mi < 4; ++mi) {
        int o = o0 + wm + mi * 16 + rb;
        float4 bo = *(const float4*)&biasc[o];
        #pragma unroll
        for (int r = 0; r < 3 + 1; ++r) {
            float br = (r == 0) ? bo.x : (r == 1) ? bo.y : (r == 2) ? bo.z : bo.w;
            #pragma unroll
            for (int ni = 0; ni < 4; ++ni) {
                int p = p0 + wn + ni * 16 + col;
                Out[(((size_t)(n * 256 + o + r)) << 12) + p] = acc[mi][ni][r] + br;
            }
        }
    }
}

// ------------- xbar (cnt-weighted sums of x rows) + posbar (grid 256 x 9)
__global__ __launch_bounds__(256) void xbar_kernel(
    const float* __restrict__ x, const float* __restrict__ pos,
    float* __restrict__ xbar_all, float* __restrict__ xbar6,
    float* __restrict__ posbar, float* __restrict__ posbar6)
{
    int c = blockIdx.x, n = blockIdx.y, tid = threadIdx.x;
    const float* src = (n < 8) ? x + (((size_t)(n * 256 + c)) << 12)
                               : pos + (((size_t)c) << 12);
    float sa = 0.f, s6 = 0.f;
    #pragma unroll
    for (int k = 0; k < 4; ++k) {
        int f4 = tid + k * 256;
        float4 v = *(const float4*)(src + f4 * 4);
        int p = f4 * 4;
        int y = p >> 6, xx = p & 63;
        float cy = (float)cnt1f(y, 10, 14, 6);
        float c0_ = cy * (float)cnt1f(xx + 0, 10, 14, 6);
        float c1_ = cy * (float)cnt1f(xx + 1, 10, 14, 6);
        float c2_ = cy * (float)cnt1f(xx + 2, 10, 14, 6);
        float c3_ = cy * (float)cnt1f(xx + 3, 10, 14, 6);
        sa += v.x + v.y + v.z + v.w;
        s6 += c0_ * v.x + c1_ * v.y + c2_ * v.z + c3_ * v.w;
    }
    __shared__ float red[256];
    float ra = blockReduceSum(sa, red);
    float r6 = blockReduceSum(s6, red);
    if (tid == 0) {
        if (n < 8) { xbar_all[n * 256 + c] = ra; xbar6[n * 256 + c] = r6; }
        else       { posbar[c] = ra;             posbar6[c] = r6; }
    }
}

// --------------------------- qdot_i[n,p] = g_i.x + wq.pos + c0_i (grid 16x8)
__global__ __launch_bounds__(256) void qdot_kernel(
    const float* __restrict__ x, const float* __restrict__ pos,
    const float* __restrict__ g, const float* __restrict__ c0,
    const float* __restrict__ wq, float* __restrict__ qdot)
{
    int n = blockIdx.y, tid = threadIdx.x;
    int p = blockIdx.x * 256 + tid;
    __shared__ float gl[768];
    __shared__ float wql[256];
    gl[tid] = g[tid]; gl[256 + tid] = g[256 + tid]; gl[512 + tid] = g[512 + tid];
    wql[tid] = wq[tid];
    __syncthreads();
    const float* xp = x + (((size_t)n) << 20) + p;
    const float* pp = pos + p;
    float q0 = 0.f, q1 = 0.f, q2 = 0.f, qp = 0.f;
    #pragma unroll 4
    for (int c = 0; c < 256; ++c) {
        float xv = xp[(size_t)c << 12];
        float pv = pp[(size_t)c << 12];
        q0 = fmaf(gl[c], xv, q0);
        q1 = fmaf(gl[256 + c], xv, q1);
        q2 = fmaf(gl[512 + c], xv, q2);
        qp = fmaf(wql[c], pv, qp);
    }
    qdot[((0 * 8 + n) << 12) + p] = q0 + qp + c0[0];
    qdot[((1 * 8 + n) << 12) + p] = q1 + qp + c0[1];
    qdot[((2 * 8 + n) << 12) + p] = q2 + qp + c0[2];
}

// ------------- ubar_i[n,c] = W_exp_i[c,:]@xbar_i + b*L_i + posbar_i (grid 3x8)
__global__ __launch_bounds__(256) void ubar_mv(
    const float* __restrict__ W_exp, const float* __restrict__ b_exp,
    const float* __restrict__ xbar_all, const float* __restrict__ xbar6,
    const float* __restrict__ posbar, const float* __restrict__ posbar6,
    float* __restrict__ ubar)
{
    int i = blockIdx.x, n = blockIdx.y, tid = threadIdx.x;
    __shared__ float xb[256];
    const float* xsrc = (i < 2) ? xbar_all : xbar6;
    xb[tid] = xsrc[n * 256 + tid];
    __syncthreads();
    int win = 2 * (i + 1), sh = 64 / win, kh = sh + 64 % win;
    float Li = (float)(win * win * kh * kh);
    const float* pb = (i < 2) ? posbar : posbar6;
    float acc = b_exp[i * 256 + tid] * Li + pb[tid];
    const float* Wr = W_exp + ((size_t)(i * 256 + tid)) * 256;
    for (int cin = 0; cin < 256; ++cin) acc = fmaf(Wr[cin], xb[cin], acc);
    ubar[(i * 8 + n) * 256 + tid] = acc;
}

// --------------------------- softmax stats, spq, w_eff, b_eff (grid 3x8)
__global__ __launch_bounds__(256) void pass_b(
    const float* __restrict__ qdot, const float* __restrict__ ubar_raw,
    const float* __restrict__ sp_wq_w, const float* __restrict__ sp_wq_b,
    const float* __restrict__ sp_wv_w, const float* __restrict__ sp_wv_b,
    float* __restrict__ Mn, float* __restrict__ invZn,
    float* __restrict__ w_eff, float* __restrict__ b_eff)
{
    int i = blockIdx.x, n = blockIdx.y, tid = threadIdx.x;
    int b = i * 8 + n;
    int win = 2 * (i + 1), sh = 64 / win, kh = sh + 64 % win;
    float invL = 1.f / (float)(win * win * kh * kh);
    const float* qd = qdot + (((size_t)b) << 12);
    __shared__ float red[256];
    __shared__ float ub[256];
    __shared__ float spq[128];
    float m = -1e30f;
    for (int p = tid; p < HW; p += 256) m = fmaxf(m, qd[p]);
    red[tid] = m; __syncthreads();
    for (int s = 128; s > 0; s >>= 1) { if (tid < s) red[tid] = fmaxf(red[tid], red[tid + s]); __syncthreads(); }
    float M = red[0]; __syncthreads();
    float z = 0.f;
    for (int p = tid; p < HW; p += 256) {
        int y = p >> 6, xx = p & 63;
        float cf = (float)(cnt1f(y, sh, kh, win) * cnt1f(xx, sh, kh, win));
        z += cf * expf(qd[p] - M);
    }
    red[tid] = z; __syncthreads();
    for (int s = 128; s > 0; s >>= 1) { if (tid < s) red[tid] += red[tid + s]; __syncthreads(); }
    float Z = red[0]; __syncthreads();
    if (tid == 0) { Mn[b] = M; invZn[b] = 1.f / Z; }
    ub[tid] = ubar_raw[b * 256 + tid] * invL;
    __syncthreads();
    float sl = -1e30f;
    if (tid < 128) {
        float a = sp_wq_b[tid];
        for (int c = 0; c < 256; ++c) a = fmaf(sp_wq_w[tid * 256 + c], ub[c], a);
        sl = a;
    }
    red[tid] = sl; __syncthreads();
    for (int s = 128; s > 0; s >>= 1) { if (tid < s) red[tid] = fmaxf(red[tid], red[tid + s]); __syncthreads(); }
    float m2 = red[0]; __syncthreads();
    float e = (tid < 128) ? expf(sl - m2) : 0.f;
    red[tid] = e; __syncthreads();
    for (int s = 128; s > 0; s >>= 1) { if (tid < s) red[tid] += red[tid + s]; __syncthreads(); }
    float S2 = red[0]; __syncthreads();
    if (tid < 128) spq[tid] = e / S2;
    __syncthreads();
    float a = 0.f;
    for (int c2 = 0; c2 < 128; ++c2) a = fmaf(spq[c2], sp_wv_w[c2 * 256 + tid], a);
    w_eff[b * 256 + tid] = a;
    if (tid == 0) {
        float bb = 0.f;
        for (int c2 = 0; c2 < 128; ++c2) bb = fmaf(spq[c2], sp_wv_b[c2], bb);
        b_eff[b] = bb;
    }
}

// ------------- h_i[n,:] = W_exp_i^T @ w_eff ; btot = b_eff + w_eff.b (grid 3x8)
__global__ __launch_bounds__(256) void h_kernel(
    const float* __restrict__ W_exp, const float* __restrict__ b_exp,
    const float* __restrict__ weff, const float* __restrict__ beff,
    float* __restrict__ h, float* __restrict__ btot)
{
    int i = blockIdx.x, n = blockIdx.y, tid = threadIdx.x;
    int b = i * 8 + n;
    __shared__ float we[256];
    we[tid] = weff[b * 256 + tid];
    __syncthreads();
    const float* Wb = W_exp + (size_t)i * 256 * 256;
    float acc = 0.f;
    for (int oc = 0; oc < 256; ++oc) acc = fmaf(we[oc], Wb[oc * 256 + tid], acc);
    h[b * 256 + tid] = acc;
    if (tid == 0) {
        float bb = beff[b];
        for (int oc = 0; oc < 256; ++oc) bb = fmaf(we[oc], b_exp[i * 256 + oc], bb);
        btot[b] = bb;
    }
}

// --------- spw_i = sigmoid(h_i.x + w_eff.pos + btot); t_i = cnt*softmax (16x8)
__global__ __launch_bounds__(256) void spw_t_kernel(
    const float* __restrict__ x, const float* __restrict__ pos,
    const float* __restrict__ h, const float* __restrict__ weff,
    const float* __restrict__ qdot, const float* __restrict__ Mn,
    const float* __restrict__ invZn, const float* __restrict__ btot,
    float* __restrict__ spw, float* __restrict__ tbuf)
{
    int n = blockIdx.y, tid = threadIdx.x;
    int p = blockIdx.x * 256 + tid;
    __shared__ float hl[768], wl[768];
    #pragma unroll
    for (int i = 0; i < 3; ++i) {
        hl[i * 256 + tid] = h[(i * 8 + n) * 256 + tid];
        wl[i * 256 + tid] = weff[(i * 8 + n) * 256 + tid];
    }
    __syncthreads();
    const float* xp = x + (((size_t)n) << 20) + p;
    const float* pp = pos + p;
    float a0 = 0.f, a1 = 0.f, a2 = 0.f;
    #pragma unroll 4
    for (int c = 0; c < 256; ++c) {
        float xv = xp[(size_t)c << 12];
        float pv = pp[(size_t)c << 12];
        a0 += hl[c] * xv + wl[c] * pv;
        a1 += hl[256 + c] * xv + wl[256 + c] * pv;
        a2 += hl[512 + c] * xv + wl[512 + c] * pv;
    }
    int y = p >> 6, xx = p & 63;
    float a[3] = {a0, a1, a2};
    #pragma unroll
    for (int i = 0; i < 3; ++i) {
        int b = i * 8 + n;
        int win = 2 * (i + 1), sh = 64 / win, kh = sh + 64 % win;
        float cf = (float)(cnt1f(y, sh, kh, win) * cnt1f(xx, sh, kh, win));
        int idx = (b << 12) + p;
        spw[idx] = 1.f / (1.f + expf(-(a[i] + btot[b])));
        tbuf[idx] = cf * expf(qdot[idx] - Mn[b]) * invZn[b];
    }
}

// ------------- xq_i[n,c] = sum t_i*x ; posq_i[n,c] = sum t_i*pos (grid 256x8)
__global__ __launch_bounds__(256) void xq_kernel(
    const float* __restrict__ x, const float* __restrict__ pos,
    const float* __restrict__ tbuf, float* __restrict__ xq, float* __restrict__ posq)
{
    int c = blockIdx.x, n = blockIdx.y, tid = threadIdx.x;
    const float* xr = x + (((size_t)(n * 256 + c)) << 12);
    const float* pr = pos + (((size_t)c) << 12);
    float ax[3] = {0.f, 0.f, 0.f}, ap[3] = {0.f, 0.f, 0.f};
    #pragma unroll
    for (int k = 0; k < 4; ++k) {
        int f4 = tid + k * 256;
        float4 xv = *(const float4*)(xr + f4 * 4);
        float4 pv = *(const float4*)(pr + f4 * 4);
        #pragma unroll
        for (int i = 0; i < 3; ++i) {
            float4 tv = *(const float4*)(tbuf + (((size_t)(i * 8 + n)) << 12) + f4 * 4);
            ax[i] += tv.x * xv.x + tv.y * xv.y + tv.z * xv.z + tv.w * xv.w;
            ap[i] += tv.x * pv.x + tv.y * pv.y + tv.z * pv.z + tv.w * pv.w;
        }
    }
    __shared__ float red[256];
    #pragma unroll
    for (int i = 0; i < 3; ++i) {
        float rx = blockReduceSum(ax[i], red);
        float rp = blockReduceSum(ap[i], red);
        if (tid == 0) { xq[(i * 8 + n) * 256 + c] = rx; posq[(i * 8 + n) * 256 + c] = rp; }
    }
}

// ------------- uq_i[n,c] = W_exp_i[c,:]@xq_i + b + posq_i (grid 3x8)
__global__ __launch_bounds__(256) void uq_mv(
    const float* __restrict__ W_exp, const float* __restrict__ b_exp,
    const float* __restrict__ xq, const float* __restrict__ posq,
    float* __restrict__ uq)
{
    int i = blockIdx.x, n = blockIdx.y, tid = threadIdx.x;
    int b = i * 8 + n;
    __shared__ float xb[256];
    xb[tid] = xq[b * 256 + tid];
    __syncthreads();
    float acc = b_exp[i * 256 + tid] + posq[b * 256 + tid];
    const float* Wr = W_exp + ((size_t)(i * 256 + tid)) * 256;
    for (int cin = 0; cin < 256; ++cin) acc = fmaf(Wr[cin], xb[cin], acc);
    uq[b * 256 + tid] = acc;
}

// --------------------------------------- z -> wz -> LN -> ch_w (grid 3x8)
__global__ __launch_bounds__(256) void pass_d(
    const float* __restrict__ uq,
    const float* __restrict__ ch_wv_w, const float* __restrict__ ch_wv_b,
    const float* __restrict__ ch_wz_w, const float* __restrict__ ch_wz_b,
    const float* __restrict__ ln_g, const float* __restrict__ ln_b,
    float* __restrict__ ch_w)
{
    int i = blockIdx.x, n = blockIdx.y, tid = threadIdx.x;
    int b = i * 8 + n;
    __shared__ float zz[128];
    __shared__ float red[256];
    __shared__ float uql[256];
    uql[tid] = uq[b * 256 + tid];
    __syncthreads();
    if (tid < 128) {
        float a = ch_wv_b[tid];
        for (int c = 0; c < 256; ++c) a = fmaf(ch_wv_w[tid * 256 + c], uql[c], a);
        zz[tid] = a;
    }
    __syncthreads();
    float wz = ch_wz_b[tid];
    for (int c2 = 0; c2 < 128; ++c2) wz = fmaf(ch_wz_w[tid * 128 + c2], zz[c2], wz);
    red[tid] = wz; __syncthreads();
    for (int s = 128; s > 0; s >>= 1) { if (tid < s) red[tid] += red[tid + s]; __syncthreads(); }
    float mean = red[0] * (1.f / 256.f); __syncthreads();
    float d = wz - mean;
    red[tid] = d * d; __syncthreads();
    for (int s = 128; s > 0; s >>= 1) { if (tid < s) red[tid] += red[tid + s]; __syncthreads(); }
    float var = red[0] * (1.f / 256.f);
    float xn = d / sqrtf(var + 1e-5f);
    ch_w[b * 256 + tid] = 1.f / (1.f + expf(-(xn * ln_g[tid] + ln_b[tid])));
}

// ---- combT = expxT + (expxT+posT)*(chw+spw), in-place bf16 (grid 1536 x 8)
__global__ __launch_bounds__(256) void pass_e(
    ushort_t* __restrict__ exT, const float* __restrict__ posT,
    const float* __restrict__ chw, const float* __restrict__ spw)
{
    int n = blockIdx.y;
    int t = blockIdx.x * 256 + threadIdx.x;     // < 4096*96
    int c8 = t % 96;
    int p  = t / 96;
    int c768 = c8 * 8;
    int i = c768 >> 8;
    int c = c768 & 255;
    ushort_t* ep = exT + (((size_t)((n << 12) + p)) * 768) + c768;
    ushort8v ev = *(const ushort8v*)ep;
    float4 q0 = *(const float4*)&posT[p * 256 + c];
    float4 q1 = *(const float4*)&posT[p * 256 + c + 4];
    float4 w0 = *(const float4*)&chw[(i * 8 + n) * 256 + c];
    float4 w1 = *(const float4*)&chw[(i * 8 + n) * 256 + c + 4];
    float s = spw[((i * 8 + n) << 12) + p];
    float e0 = bf2f(ev[0]), e1 = bf2f(ev[1]), e2 = bf2f(ev[2]), e3 = bf2f(ev[3]);
    float e4 = bf2f(ev[4]), e5 = bf2f(ev[5]), e6 = bf2f(ev[6]), e7 = bf2f(ev[7]);
    ushort8v o;
    o[0] = f2bf(e0 + (e0 + q0.x) * (w0.x + s));
    o[1] = f2bf(e1 + (e1 + q0.y) * (w0.y + s));
    o[2] = f2bf(e2 + (e2 + q0.z) * (w0.z + s));
    o[3] = f2bf(e3 + (e3 + q0.w) * (w0.w + s));
    o[4] = f2bf(e4 + (e4 + q1.x) * (w1.x + s));
    o[5] = f2bf(e5 + (e5 + q1.y) * (w1.y + s));
    o[6] = f2bf(e6 + (e6 + q1.z) * (w1.z + s));
    o[7] = f2bf(e7 + (e7 + q1.w) * (w1.w + s));
    *(ushort8v*)ep = o;
}

// ---------------------------------------------------------------------------
extern "C" void kernel_launch(void* const* d_in, const int* in_sizes, int n_in,
                              void* d_out, int out_size, void* d_ws, size_t ws_size,
                              hipStream_t stream) {
    const float* x        = (const float*)d_in[0];
    const float* w_exp    = (const float*)d_in[1];
    const float* b_exp    = (const float*)d_in[2];
    const float* w_res    = (const float*)d_in[3];
    const float* b_res    = (const float*)d_in[4];
    const float* w_fus    = (const float*)d_in[5];
    const float* b_fus    = (const float*)d_in[6];
    const float* ch_wv_w  = (const float*)d_in[7];
    const float* ch_wv_b  = (const float*)d_in[8];
    const float* ch_wq_w  = (const float*)d_in[9];
    const float* ch_wq_b  = (const float*)d_in[10];
    const float* ch_wz_w  = (const float*)d_in[11];
    const float* ch_wz_b  = (const float*)d_in[12];
    const float* ln_g     = (const float*)d_in[13];
    const float* ln_b     = (const float*)d_in[14];
    const float* sp_wv_w  = (const float*)d_in[15];
    const float* sp_wv_b  = (const float*)d_in[16];
    const float* sp_wq_w  = (const float*)d_in[17];
    const float* sp_wq_b  = (const float*)d_in[18];
    float* out = (float*)d_out;
    float* ws  = (float*)d_ws;

    // workspace layout (float offsets); total ~19.5M floats = 78 MB
    float*    pos   = ws + 0;          // 1048576
    float*    posT  = ws + 1048576;    // 1048576
    ushort_t* xbT   = (ushort_t*)(ws + 2097152);   // 8,388,608 ushorts
    ushort_t* exT   = (ushort_t*)(ws + 6291456);   // 25,165,824 ushorts
    ushort_t* wexpb = (ushort_t*)(ws + 18874368);  // 196,608 ushorts
    ushort_t* Wcat  = (ushort_t*)(ws + 18972672);  // 262,144 ushorts
    float*    qdot  = ws + 19103744;   // 98304
    float*    tbuf  = ws + 19202048;   // 98304
    float*    spw   = ws + 19300352;   // 98304
    float*    g     = ws + 19398656;   // 768
    float*    c0    = ws + 19399424;   // 4
    float*    xba   = ws + 19399428;   // 2048
    float*    xb6   = ws + 19401476;   // 2048
    float*    pba   = ws + 19403524;   // 256
    float*    pb6   = ws + 19403780;   // 256
    float*    ubar  = ws + 19404036;   // 6144
    float*    Mn    = ws + 19410180;   // 24
    float*    iZ    = ws + 19410204;   // 24
    float*    weff  = ws + 19410228;   // 6144
    float*    beff  = ws + 19416372;   // 24
    float*    btot  = ws + 19416396;   // 24
    float*    hb    = ws + 19416420;   // 6144
    float*    xq    = ws + 19422564;   // 6144
    float*    posq  = ws + 19428708;   // 6144
    float*    uq    = ws + 19434852;   // 6144
    float*    chw   = ws + 19440996;   // 6144
    float*    biasc = ws + 19447140;   // 256

    pos_kernel<<<4096, 256, 0, stream>>>(pos);
    posT_kernel<<<4096, 256, 0, stream>>>(posT);
    trans_x<<<dim3(128, 8, 8), 256, 0, stream>>>(x, xbT);
    conv_bf16<<<768, 256, 0, stream>>>(w_exp, wexpb, 196608);
    prep_g<<<3, 256, 0, stream>>>(w_exp, b_exp, ch_wq_w, ch_wq_b, g, c0);
    prep_wcomb<<<256, 256, 0, stream>>>(w_fus, w_res, b_res, b_fus, Wcat, biasc);

    gemm_expT<<<dim3(32, 6, 8), 256, 0, stream>>>(wexpb, xbT, b_exp, exT);

    xbar_kernel<<<dim3(256, 9), 256, 0, stream>>>(x, pos, xba, xb6, pba, pb6);
    qdot_kernel<<<dim3(16, 8), 256, 0, stream>>>(x, pos, g, c0, ch_wq_w, qdot);
    ubar_mv<<<dim3(3, 8), 256, 0, stream>>>(w_exp, b_exp, xba, xb6, pba, pb6, ubar);
    pass_b<<<dim3(3, 8), 256, 0, stream>>>(qdot, ubar, sp_wq_w, sp_wq_b,
                                           sp_wv_w, sp_wv_b, Mn, iZ, weff, beff);
    h_kernel<<<dim3(3, 8), 256, 0, stream>>>(w_exp, b_exp, weff, beff, hb, btot);
    spw_t_kernel<<<dim3(16, 8), 256, 0, stream>>>(x, pos, hb, weff, qdot, Mn, iZ,
                                                  btot, spw, tbuf);
    xq_kernel<<<dim3(256, 8), 256, 0, stream>>>(x, pos, tbuf, xq, posq);
    uq_mv<<<dim3(3, 8), 256, 0, stream>>>(w_exp, b_exp, xq, posq, uq);
    pass_d<<<dim3(3, 8), 256, 0, stream>>>(uq, ch_wv_w, ch_wv_b, ch_wz_w, ch_wz_b,
                                           ln_g, ln_b, chw);

    pass_e<<<dim3(1536, 8), 256, 0, stream>>>(exT, posT, chw, spw);
    gemm_out<<<dim3(32, 2, 8), 256, 0, stream>>>(Wcat, xbT, exT, biasc, out);
}

// Round 6
// 309.028 us; speedup vs baseline: 5.3998x; 1.2741x over previous
//
#include <hip/hip_runtime.h>
#include <cstddef>

// ---------------------------------------------------------------------------
// PatchAttention, algebraically simplified + bf16 MFMA GEMMs.
// PSA gating weights (chw, spw) are linear functionals of x -> computed first
// from x directly; then ONE gemm (W_exp) writes the already-gated "combined"
// tensor via a fused epilogue; final gemm computes
//   out = [W_fus | W_fus@W_res] @ [x ; combined] + biasc.
// ---------------------------------------------------------------------------

#define HW 4096
typedef unsigned short ushort_t;
typedef __attribute__((ext_vector_type(8))) short bf16x8;
typedef __attribute__((ext_vector_type(4))) float floatx4;

__device__ __forceinline__ ushort_t f2bf(float f) {
    unsigned u = __float_as_uint(f);
    u += 0x7FFF + ((u >> 16) & 1);           // RNE
    return (ushort_t)(u >> 16);
}

__device__ __forceinline__ int cnt1f(int y, int sh, int kh, int win) {
    int t = y - kh + sh;
    int lo = t > 0 ? t / sh : 0;
    int hi = min(win - 1, y / sh);
    return hi - lo + 1;
}

__device__ __forceinline__ float posval(int f) {
    int row = f >> 8, col = f & 255;
    int a = row >> 6, b = row & 63;
    int g = col >> 6, k = col & 63;
    float omega = expf(-(float)k * (9.2103403719761836f / 64.f)); // 10000^(-k/64)
    float arg = (g < 2 ? (float)a : (float)b) * omega;
    return (g & 1) ? cosf(arg) : sinf(arg);
}

// --------------------------------------------- pos (c-major) + posT (p-major)
__global__ __launch_bounds__(256) void pos_both(
    float* __restrict__ pos, float* __restrict__ posT)
{
    int idx = blockIdx.x * 256 + threadIdx.x;      // < 1048576
    pos[idx] = posval(idx);
    int p = idx >> 8, c = idx & 255;
    posT[idx] = posval(c * 4096 + p);
}

__global__ __launch_bounds__(256) void zero_kernel(float* __restrict__ p, int n) {
    int i = blockIdx.x * 256 + threadIdx.x;
    if (i < n) p[i] = 0.f;
}

// ----------------------- x [n][c][p] fp32 -> xbT [n][p][c] bf16 (32x32 tiles)
__global__ __launch_bounds__(256) void trans_x(
    const float* __restrict__ x, ushort_t* __restrict__ xbT)
{
    __shared__ float L[32][37];
    int n = blockIdx.z;
    int p0 = blockIdx.x * 32, c0 = blockIdx.y * 32;
    int t = threadIdx.x;
    int cc = t >> 3, p4 = (t & 7) * 4;
    const float* src = x + (((size_t)(n * 256 + c0 + cc)) << 12) + p0 + p4;
    float4 v = *(const float4*)src;
    L[cc][p4] = v.x; L[cc][p4 + 1] = v.y; L[cc][p4 + 2] = v.z; L[cc][p4 + 3] = v.w;
    __syncthreads();
    int pp = t >> 3, c4 = (t & 7) * 4;
    unsigned lo = (unsigned)f2bf(L[c4][pp]) | ((unsigned)f2bf(L[c4 + 1][pp]) << 16);
    unsigned hi = (unsigned)f2bf(L[c4 + 2][pp]) | ((unsigned)f2bf(L[c4 + 3][pp]) << 16);
    *(uint2*)&xbT[(((size_t)(n << 12)) + p0 + pp) * 256 + c0 + c4] = make_uint2(lo, hi);
}

// ---------------------------------------------- fp32 -> bf16 (weights)
__global__ __launch_bounds__(256) void conv_bf16(
    const float* __restrict__ src, ushort_t* __restrict__ dst, int nelem)
{
    int i = blockIdx.x * 256 + threadIdx.x;
    if (i < nelem) dst[i] = f2bf(src[i]);
}

// ---- g_i = W_exp_i^T @ ch_wq_w ; c0_i  (k-split, atomics; grid 3 x 8)
__global__ __launch_bounds__(256) void prep_g(
    const float* __restrict__ W_exp, const float* __restrict__ b_exp,
    const float* __restrict__ wq, const float* __restrict__ wq_b,
    float* __restrict__ g, float* __restrict__ c0out)
{
    int i = blockIdx.x, ks = blockIdx.y, tid = threadIdx.x;
    __shared__ float wql[32];
    __shared__ float red[256];
    if (tid < 32) wql[tid] = wq[ks * 32 + tid];
    __syncthreads();
    const float* Wb = W_exp + ((size_t)(i * 256 + ks * 32)) * 256 + tid;
    float acc = 0.f;
    #pragma unroll 8
    for (int j = 0; j < 32; ++j) acc = fmaf(wql[j], Wb[(size_t)j * 256], acc);
    atomicAdd(&g[i * 256 + tid], acc);
    red[tid] = (tid < 32) ? wql[tid] * b_exp[i * 256 + ks * 32 + tid] : 0.f;
    __syncthreads();
    for (int s = 128; s > 0; s >>= 1) { if (tid < s) red[tid] += red[tid + s]; __syncthreads(); }
    if (tid == 0) atomicAdd(&c0out[i], red[0] + (ks == 0 ? wq_b[0] : 0.f));
}

// --- Wcat[o][0:256]=bf16(W_fus), [256:1024]=bf16(W_fus@W_res) (grid 256 x 3)
__global__ __launch_bounds__(256) void prep_wcomb(
    const float* __restrict__ W_fus, const float* __restrict__ W_res,
    const float* __restrict__ b_res, const float* __restrict__ b_fus,
    ushort_t* __restrict__ Wcat, float* __restrict__ biasc)
{
    int o = blockIdx.x, jb = blockIdx.y, tid = threadIdx.x;
    __shared__ float wrow[256];
    __shared__ float red[256];
    wrow[tid] = W_fus[o * 256 + tid];
    __syncthreads();
    int j = jb * 256 + tid;
    float acc = 0.f;
    #pragma unroll 8
    for (int c = 0; c < 256; ++c) acc = fmaf(wrow[c], W_res[(size_t)c * 768 + j], acc);
    Wcat[o * 1024 + 256 + j] = f2bf(acc);
    if (jb == 0) {
        Wcat[o * 1024 + tid] = f2bf(wrow[tid]);
        red[tid] = wrow[tid] * b_res[tid];
        __syncthreads();
        for (int s = 128; s > 0; s >>= 1) { if (tid < s) red[tid] += red[tid + s]; __syncthreads(); }
        if (tid == 0) biasc[o] = red[0] + b_fus[o];
    }
}

// ------------- xbar (cnt-weighted sums of x rows) + posbar (grid 256 x 9)
__global__ __launch_bounds__(256) void xbar_kernel(
    const float* __restrict__ x, const float* __restrict__ pos,
    float* __restrict__ xbar_all, float* __restrict__ xbar6,
    float* __restrict__ posbar, float* __restrict__ posbar6)
{
    int c = blockIdx.x, n = blockIdx.y, tid = threadIdx.x;
    const float* src = (n < 8) ? x + (((size_t)(n * 256 + c)) << 12)
                               : pos + (((size_t)c) << 12);
    float sa = 0.f, s6 = 0.f;
    #pragma unroll
    for (int k = 0; k < 4; ++k) {
        int f4 = tid + k * 256;
        float4 v = *(const float4*)(src + f4 * 4);
        int p = f4 * 4;
        int y = p >> 6, xx = p & 63;
        float cy = (float)cnt1f(y, 10, 14, 6);
        float c0_ = cy * (float)cnt1f(xx + 0, 10, 14, 6);
        float c1_ = cy * (float)cnt1f(xx + 1, 10, 14, 6);
        float c2_ = cy * (float)cnt1f(xx + 2, 10, 14, 6);
        float c3_ = cy * (float)cnt1f(xx + 3, 10, 14, 6);
        sa += v.x + v.y + v.z + v.w;
        s6 += c0_ * v.x + c1_ * v.y + c2_ * v.z + c3_ * v.w;
    }
    __shared__ float red[256];
    red[tid] = sa; __syncthreads();
    for (int s = 128; s > 0; s >>= 1) { if (tid < s) red[tid] += red[tid + s]; __syncthreads(); }
    float ra = red[0]; __syncthreads();
    red[tid] = s6; __syncthreads();
    for (int s = 128; s > 0; s >>= 1) { if (tid < s) red[tid] += red[tid + s]; __syncthreads(); }
    float r6 = red[0];
    if (tid == 0) {
        if (n < 8) { xbar_all[n * 256 + c] = ra; xbar6[n * 256 + c] = r6; }
        else       { posbar[c] = ra;             posbar6[c] = r6; }
    }
}

// --------- qdot_i[n,p] = g_i.x + wq.pos + c0_i (grid 32 x 8, 512 thr, 4-way k)
__global__ __launch_bounds__(512) void qdot_kernel(
    const float* __restrict__ x, const float* __restrict__ pos,
    const float* __restrict__ g, const float* __restrict__ c0in,
    const float* __restrict__ wq, float* __restrict__ qdot)
{
    int n = blockIdx.y, tid = threadIdx.x;
    int ph = tid & 127, cq = tid >> 7;
    int p = blockIdx.x * 128 + ph;
    __shared__ float gl[768];
    __shared__ float wql[256];
    __shared__ float4 red4[512];
    for (int k = tid; k < 768; k += 512) gl[k] = g[k];
    if (tid < 256) wql[tid] = wq[tid];
    __syncthreads();
    const float* xp = x + (((size_t)n) << 20) + p;
    const float* pp = pos + p;
    float q0 = 0.f, q1 = 0.f, q2 = 0.f, qp = 0.f;
    #pragma unroll 4
    for (int c = cq * 64; c < cq * 64 + 64; ++c) {
        float xv = xp[(size_t)c << 12];
        float pv = pp[(size_t)c << 12];
        q0 = fmaf(gl[c], xv, q0);
        q1 = fmaf(gl[256 + c], xv, q1);
        q2 = fmaf(gl[512 + c], xv, q2);
        qp = fmaf(wql[c], pv, qp);
    }
    red4[tid] = make_float4(q0, q1, q2, qp);
    __syncthreads();
    if (tid < 128) {
        float4 a = red4[tid], b = red4[128 + tid], cc = red4[256 + tid], d = red4[384 + tid];
        float rp = a.w + b.w + cc.w + d.w;
        qdot[((0 * 8 + n) << 12) + p] = a.x + b.x + cc.x + d.x + rp + c0in[0];
        qdot[((1 * 8 + n) << 12) + p] = a.y + b.y + cc.y + d.y + rp + c0in[1];
        qdot[((2 * 8 + n) << 12) + p] = a.z + b.z + cc.z + d.z + rp + c0in[2];
    }
}

// ---- ubar partials (k-split, atomics; grid 3 x 8 x 8)
__global__ __launch_bounds__(256) void ubar_split(
    const float* __restrict__ W_exp, const float* __restrict__ b_exp,
    const float* __restrict__ xbar_all, const float* __restrict__ xbar6,
    const float* __restrict__ posbar, const float* __restrict__ posbar6,
    float* __restrict__ ubar)
{
    int i = blockIdx.x, n = blockIdx.y, ks = blockIdx.z, tid = threadIdx.x;
    int b = i * 8 + n;
    __shared__ float xbl[32];
    const float* xsrc = ((i < 2) ? xbar_all : xbar6) + n * 256 + ks * 32;
    if (tid < 32) xbl[tid] = xsrc[tid];
    __syncthreads();
    const float* Wr = W_exp + ((size_t)(i * 256 + tid)) * 256 + ks * 32;
    float acc = 0.f;
    #pragma unroll 8
    for (int j = 0; j < 32; ++j) acc = fmaf(Wr[j], xbl[j], acc);
    if (ks == 0) {
        int win = 2 * (i + 1), sh = 64 / win, kh = sh + 64 % win;
        float Li = (float)(win * win * kh * kh);
        acc += b_exp[i * 256 + tid] * Li + ((i < 2) ? posbar : posbar6)[tid];
    }
    atomicAdd(&ubar[b * 256 + tid], acc);
}

// ---- softmax stats, spq, w_eff, h, btot (grid 3 x 8) [pass_b + h fused]
__global__ __launch_bounds__(256) void pass_b_h(
    const float* __restrict__ qdot, const float* __restrict__ ubar_raw,
    const float* __restrict__ sp_wq_w, const float* __restrict__ sp_wq_b,
    const float* __restrict__ sp_wv_w, const float* __restrict__ sp_wv_b,
    const float* __restrict__ W_exp, const float* __restrict__ b_exp,
    float* __restrict__ Mn, float* __restrict__ invZn,
    float* __restrict__ w_eff, float* __restrict__ h, float* __restrict__ btot)
{
    int i = blockIdx.x, n = blockIdx.y, tid = threadIdx.x;
    int b = i * 8 + n;
    int win = 2 * (i + 1), sh = 64 / win, kh = sh + 64 % win;
    float invL = 1.f / (float)(win * win * kh * kh);
    const float* qd = qdot + (((size_t)b) << 12);
    __shared__ float red[256];
    __shared__ float ub[256];
    __shared__ float spq[128];
    __shared__ float we[256];
    float m = -1e30f;
    for (int p = tid; p < HW; p += 256) m = fmaxf(m, qd[p]);
    red[tid] = m; __syncthreads();
    for (int s = 128; s > 0; s >>= 1) { if (tid < s) red[tid] = fmaxf(red[tid], red[tid + s]); __syncthreads(); }
    float M = red[0]; __syncthreads();
    float z = 0.f;
    for (int p = tid; p < HW; p += 256) {
        int y = p >> 6, xx = p & 63;
        float cf = (float)(cnt1f(y, sh, kh, win) * cnt1f(xx, sh, kh, win));
        z += cf * expf(qd[p] - M);
    }
    red[tid] = z; __syncthreads();
    for (int s = 128; s > 0; s >>= 1) { if (tid < s) red[tid] += red[tid + s]; __syncthreads(); }
    float Z = red[0]; __syncthreads();
    if (tid == 0) { Mn[b] = M; invZn[b] = 1.f / Z; }
    ub[tid] = ubar_raw[b * 256 + tid] * invL;
    __syncthreads();
    float sl = -1e30f;
    if (tid < 128) {
        float a = sp_wq_b[tid];
        #pragma unroll 8
        for (int c = 0; c < 256; ++c) a = fmaf(sp_wq_w[tid * 256 + c], ub[c], a);
        sl = a;
    }
    red[tid] = sl; __syncthreads();
    for (int s = 128; s > 0; s >>= 1) { if (tid < s) red[tid] = fmaxf(red[tid], red[tid + s]); __syncthreads(); }
    float m2 = red[0]; __syncthreads();
    float e = (tid < 128) ? expf(sl - m2) : 0.f;
    red[tid] = e; __syncthreads();
    for (int s = 128; s > 0; s >>= 1) { if (tid < s) red[tid] += red[tid + s]; __syncthreads(); }
    float S2 = red[0]; __syncthreads();
    if (tid < 128) spq[tid] = e / S2;
    __syncthreads();
    float a = 0.f;
    #pragma unroll 8
    for (int c2 = 0; c2 < 128; ++c2) a = fmaf(spq[c2], sp_wv_w[c2 * 256 + tid], a);
    w_eff[b * 256 + tid] = a;
    we[tid] = a;
    // beff = spq . sp_wv_b (parallel reduction)
    red[tid] = (tid < 128) ? spq[tid] * sp_wv_b[tid] : 0.f;
    __syncthreads();
    for (int s = 128; s > 0; s >>= 1) { if (tid < s) red[tid] += red[tid + s]; __syncthreads(); }
    float beff = red[0]; __syncthreads();
    // h = W_exp_i^T @ we  (coalesced column reads)
    const float* Wb = W_exp + (size_t)i * 65536 + tid;
    float hacc = 0.f;
    #pragma unroll 8
    for (int oc = 0; oc < 256; ++oc) hacc = fmaf(we[oc], Wb[(size_t)oc * 256], hacc);
    h[b * 256 + tid] = hacc;
    // btot = beff + we . b_exp_i
    red[tid] = we[tid] * b_exp[i * 256 + tid];
    __syncthreads();
    for (int s = 128; s > 0; s >>= 1) { if (tid < s) red[tid] += red[tid + s]; __syncthreads(); }
    if (tid == 0) btot[b] = red[0] + beff;
}

// --- spw_i = sigmoid(h_i.x + weff.pos + btot); t_i = cnt*softmax (32x8, 512thr)
__global__ __launch_bounds__(512) void spw_t_kernel(
    const float* __restrict__ x, const float* __restrict__ pos,
    const float* __restrict__ h, const float* __restrict__ weff,
    const float* __restrict__ qdot, const float* __restrict__ Mn,
    const float* __restrict__ invZn, const float* __restrict__ btot,
    float* __restrict__ spw, float* __restrict__ tbuf)
{
    int n = blockIdx.y, tid = threadIdx.x;
    int ph = tid & 127, cq = tid >> 7;
    int p = blockIdx.x * 128 + ph;
    __shared__ float hl[768], wl[768];
    __shared__ float4 red4[512];
    for (int k = tid; k < 768; k += 512) {
        int i = k >> 8, c = k & 255;
        hl[k] = h[(i * 8 + n) * 256 + c];
        wl[k] = weff[(i * 8 + n) * 256 + c];
    }
    __syncthreads();
    const float* xp = x + (((size_t)n) << 20) + p;
    const float* pp = pos + p;
    float a0 = 0.f, a1 = 0.f, a2 = 0.f;
    #pragma unroll 4
    for (int c = cq * 64; c < cq * 64 + 64; ++c) {
        float xv = xp[(size_t)c << 12];
        float pv = pp[(size_t)c << 12];
        a0 += hl[c] * xv + wl[c] * pv;
        a1 += hl[256 + c] * xv + wl[256 + c] * pv;
        a2 += hl[512 + c] * xv + wl[512 + c] * pv;
    }
    red4[tid] = make_float4(a0, a1, a2, 0.f);
    __syncthreads();
    if (tid < 128) {
        float4 aa = red4[tid], bb = red4[128 + tid], cc = red4[256 + tid], dd = red4[384 + tid];
        float av[3] = {aa.x + bb.x + cc.x + dd.x,
                       aa.y + bb.y + cc.y + dd.y,
                       aa.z + bb.z + cc.z + dd.z};
        int y = p >> 6, xx = p & 63;
        #pragma unroll
        for (int i = 0; i < 3; ++i) {
            int b = i * 8 + n;
            int win = 2 * (i + 1), sh = 64 / win, kh = sh + 64 % win;
            float cf = (float)(cnt1f(y, sh, kh, win) * cnt1f(xx, sh, kh, win));
            int idx = (b << 12) + p;
            spw[idx] = 1.f / (1.f + expf(-(av[i] + btot[b])));
            tbuf[idx] = cf * expf(qdot[idx] - Mn[b]) * invZn[b];
        }
    }
}

// ------------- xq_i[n,c] = sum t_i*x ; posq_i[n,c] = sum t_i*pos (grid 256x8)
__global__ __launch_bounds__(256) void xq_kernel(
    const float* __restrict__ x, const float* __restrict__ pos,
    const float* __restrict__ tbuf, float* __restrict__ xq, float* __restrict__ posq)
{
    int c = blockIdx.x, n = blockIdx.y, tid = threadIdx.x;
    const float* xr = x + (((size_t)(n * 256 + c)) << 12);
    const float* pr = pos + (((size_t)c) << 12);
    float ax[3] = {0.f, 0.f, 0.f}, ap[3] = {0.f, 0.f, 0.f};
    #pragma unroll
    for (int k = 0; k < 4; ++k) {
        int f4 = tid + k * 256;
        float4 xv = *(const float4*)(xr + f4 * 4);
        float4 pv = *(const float4*)(pr + f4 * 4);
        #pragma unroll
        for (int i = 0; i < 3; ++i) {
            float4 tv = *(const float4*)(tbuf + (((size_t)(i * 8 + n)) << 12) + f4 * 4);
            ax[i] += tv.x * xv.x + tv.y * xv.y + tv.z * xv.z + tv.w * xv.w;
            ap[i] += tv.x * pv.x + tv.y * pv.y + tv.z * pv.z + tv.w * pv.w;
        }
    }
    __shared__ float red[256];
    #pragma unroll
    for (int i = 0; i < 3; ++i) {
        red[tid] = ax[i]; __syncthreads();
        for (int s = 128; s > 0; s >>= 1) { if (tid < s) red[tid] += red[tid + s]; __syncthreads(); }
        float rx = red[0]; __syncthreads();
        red[tid] = ap[i]; __syncthreads();
        for (int s = 128; s > 0; s >>= 1) { if (tid < s) red[tid] += red[tid + s]; __syncthreads(); }
        float rp = red[0]; __syncthreads();
        if (tid == 0) { xq[(i * 8 + n) * 256 + c] = rx; posq[(i * 8 + n) * 256 + c] = rp; }
    }
}

// ---- uq = W_exp_i@xq + b + posq; z->wz->LN->sigmoid->chw (grid 3x8) [fused]
__global__ __launch_bounds__(256) void pass_d_uq(
    const float* __restrict__ W_exp, const float* __restrict__ b_exp,
    const float* __restrict__ xq, const float* __restrict__ posq,
    const float* __restrict__ ch_wv_w, const float* __restrict__ ch_wv_b,
    const float* __restrict__ ch_wz_w, const float* __restrict__ ch_wz_b,
    const float* __restrict__ ln_g, const float* __restrict__ ln_b,
    float* __restrict__ ch_w)
{
    int i = blockIdx.x, n = blockIdx.y, tid = threadIdx.x;
    int b = i * 8 + n;
    __shared__ float xql[256];
    __shared__ float uql[256];
    __shared__ float zz[128];
    __shared__ float red[256];
    xql[tid] = xq[b * 256 + tid];
    __syncthreads();
    float acc = b_exp[i * 256 + tid] + posq[b * 256 + tid];
    const float* Wr = W_exp + ((size_t)(i * 256 + tid)) * 256;
    #pragma unroll 8
    for (int cin = 0; cin < 256; ++cin) acc = fmaf(Wr[cin], xql[cin], acc);
    uql[tid] = acc;
    __syncthreads();
    if (tid < 128) {
        float a = ch_wv_b[tid];
        #pragma unroll 8
        for (int c = 0; c < 256; ++c) a = fmaf(ch_wv_w[tid * 256 + c], uql[c], a);
        zz[tid] = a;
    }
    __syncthreads();
    float wz = ch_wz_b[tid];
    #pragma unroll 8
    for (int c2 = 0; c2 < 128; ++c2) wz = fmaf(ch_wz_w[tid * 128 + c2], zz[c2], wz);
    red[tid] = wz; __syncthreads();
    for (int s = 128; s > 0; s >>= 1) { if (tid < s) red[tid] += red[tid + s]; __syncthreads(); }
    float mean = red[0] * (1.f / 256.f); __syncthreads();
    float d = wz - mean;
    red[tid] = d * d; __syncthreads();
    for (int s = 128; s > 0; s >>= 1) { if (tid < s) red[tid] += red[tid + s]; __syncthreads(); }
    float var = red[0] * (1.f / 256.f);
    float xn = d / sqrtf(var + 1e-5f);
    ch_w[b * 256 + tid] = 1.f / (1.f + expf(-(xn * ln_g[tid] + ln_b[tid])));
}

// ---- MFMA GEMM 1 (fused epilogue): exT = gated "combined", bf16 [n][p][768]
//   e = (W_exp@x+b);  combined = e + (e + posT)*(chw + spw)
__global__ __launch_bounds__(256) void gemm_expT(
    const ushort_t* __restrict__ Wb, const ushort_t* __restrict__ XT,
    const float* __restrict__ bias, const float* __restrict__ posT,
    const float* __restrict__ chw, const float* __restrict__ spw,
    ushort_t* __restrict__ OutT)
{
    __shared__ ushort_t As[128 * 40];
    __shared__ ushort_t Bs[128 * 40];
    int n = blockIdx.z;
    int p0 = blockIdx.x * 128;
    int o0 = blockIdx.y * 128;
    int t = threadIdx.x;
    int lane = t & 63, wave = t >> 6;
    int wm = (wave & 1) * 64, wn = (wave >> 1) * 64;
    int lr = lane & 15, lk = (lane >> 4) * 8;
    int ar = t >> 2, ac = (t & 3) * 8;
    const ushort_t* A0 = Wb + (size_t)(o0 + ar) * 256 + ac;
    const ushort_t* A1 = Wb + (size_t)(o0 + ar + 64) * 256 + ac;
    const ushort_t* B0 = XT + (((size_t)(n << 12)) + p0 + ar) * 256 + ac;
    const ushort_t* B1 = XT + (((size_t)(n << 12)) + p0 + ar + 64) * 256 + ac;
    floatx4 acc[4][4] = {};
    for (int k0 = 0; k0 < 256; k0 += 32) {
        uint4 a0 = *(const uint4*)(A0 + k0);
        uint4 a1 = *(const uint4*)(A1 + k0);
        uint4 b0 = *(const uint4*)(B0 + k0);
        uint4 b1 = *(const uint4*)(B1 + k0);
        __syncthreads();
        *(uint4*)&As[ar * 40 + ac] = a0;
        *(uint4*)&As[(ar + 64) * 40 + ac] = a1;
        *(uint4*)&Bs[ar * 40 + ac] = b0;
        *(uint4*)&Bs[(ar + 64) * 40 + ac] = b1;
        __syncthreads();
        bf16x8 af[4], bfr[4];
        #pragma unroll
        for (int mi = 0; mi < 4; ++mi)
            af[mi] = *(const bf16x8*)&As[(wm + mi * 16 + lr) * 40 + lk];
        #pragma unroll
        for (int ni = 0; ni < 4; ++ni)
            bfr[ni] = *(const bf16x8*)&Bs[(wn + ni * 16 + lr) * 40 + lk];
        #pragma unroll
        for (int mi = 0; mi < 4; ++mi)
            #pragma unroll
            for (int ni = 0; ni < 4; ++ni)
                acc[mi][ni] = __builtin_amdgcn_mfma_f32_16x16x32_bf16(
                    af[mi], bfr[ni], acc[mi][ni], 0, 0, 0);
    }
    int col = lane & 15, rb = (lane >> 4) * 4;
    int ibr = o0 >> 8;                       // branch index, constant per block
    int bi = ibr * 8 + n;
    float sv[4]; int pv_[4];
    #pragma unroll
    for (int ni = 0; ni < 4; ++ni) {
        int p = p0 + wn + ni * 16 + col;
        pv_[ni] = p;
        sv[ni] = spw[(bi << 12) + p];
    }
    #pragma unroll
    for (int mi = 0; mi < 4; ++mi) {
        int o = o0 + wm + mi * 16 + rb;
        int c = o & 255;
        float4 bo = *(const float4*)&bias[o];
        float4 cw = *(const float4*)&chw[bi * 256 + c];
        #pragma unroll
        for (int ni = 0; ni < 4; ++ni) {
            int p = pv_[ni];
            float4 q = *(const float4*)&posT[p * 256 + c];
            floatx4 v = acc[mi][ni];
            float s = sv[ni];
            float e0 = v[0] + bo.x, e1 = v[1] + bo.y, e2 = v[2] + bo.z, e3 = v[3] + bo.w;
            float r0 = e0 + (e0 + q.x) * (cw.x + s);
            float r1 = e1 + (e1 + q.y) * (cw.y + s);
            float r2 = e2 + (e2 + q.z) * (cw.z + s);
            float r3 = e3 + (e3 + q.w) * (cw.w + s);
            unsigned lo = (unsigned)f2bf(r0) | ((unsigned)f2bf(r1) << 16);
            unsigned hi = (unsigned)f2bf(r2) | ((unsigned)f2bf(r3) << 16);
            *(uint2*)&OutT[(((size_t)(n << 12)) + p) * 768 + o] = make_uint2(lo, hi);
        }
    }
}

// ---- MFMA GEMM 2: out = Wcat @ [x ; combined] + biasc, fp32 [n][256][4096]
__global__ __launch_bounds__(256) void gemm_out(
    const ushort_t* __restrict__ Wcat, const ushort_t* __restrict__ XT,
    const ushort_t* __restrict__ CT, const float* __restrict__ biasc,
    float* __restrict__ Out)
{
    __shared__ ushort_t As[128 * 40];
    __shared__ ushort_t Bs[128 * 40];
    int n = blockIdx.z;
    int p0 = blockIdx.x * 128;
    int o0 = blockIdx.y * 128;
    int t = threadIdx.x;
    int lane = t & 63, wave = t >> 6;
    int wm = (wave & 1) * 64, wn = (wave >> 1) * 64;
    int lr = lane & 15, lk = (lane >> 4) * 8;
    int ar = t >> 2, ac = (t & 3) * 8;
    const ushort_t* A0 = Wcat + (size_t)(o0 + ar) * 1024 + ac;
    const ushort_t* A1 = Wcat + (size_t)(o0 + ar + 64) * 1024 + ac;
    const ushort_t* BX0 = XT + (((size_t)(n << 12)) + p0 + ar) * 256 + ac;
    const ushort_t* BX1 = XT + (((size_t)(n << 12)) + p0 + ar + 64) * 256 + ac;
    const ushort_t* BC0 = CT + (((size_t)(n << 12)) + p0 + ar) * 768 + ac;
    const ushort_t* BC1 = CT + (((size_t)(n << 12)) + p0 + ar + 64) * 768 + ac;
    floatx4 acc[4][4] = {};
    for (int k0 = 0; k0 < 1024; k0 += 32) {
        const ushort_t* pb0 = (k0 < 256) ? (BX0 + k0) : (BC0 + (k0 - 256));
        const ushort_t* pb1 = (k0 < 256) ? (BX1 + k0) : (BC1 + (k0 - 256));
        uint4 a0 = *(const uint4*)(A0 + k0);
        uint4 a1 = *(const uint4*)(A1 + k0);
        uint4 b0 = *(const uint4*)pb0;
        uint4 b1 = *(const uint4*)pb1;
        __syncthreads();
        *(uint4*)&As[ar * 40 + ac] = a0;
        *(uint4*)&As[(ar + 64) * 40 + ac] = a1;
        *(uint4*)&Bs[ar * 40 + ac] = b0;
        *(uint4*)&Bs[(ar + 64) * 40 + ac] = b1;
        __syncthreads();
        bf16x8 af[4], bfr[4];
        #pragma unroll
        for (int mi = 0; mi < 4; ++mi)
            af[mi] = *(const bf16x8*)&As[(wm + mi * 16 + lr) * 40 + lk];
        #pragma unroll
        for (int ni = 0; ni < 4; ++ni)
            bfr[ni] = *(const bf16x8*)&Bs[(wn + ni * 16 + lr) * 40 + lk];
        #pragma unroll
        for (int mi = 0; mi < 4; ++mi)
            #pragma unroll
            for (int ni = 0; ni < 4; ++ni)
                acc[mi][ni] = __builtin_amdgcn_mfma_f32_16x16x32_bf16(
                    af[mi], bfr[ni], acc[mi][ni], 0, 0, 0);
    }
    int col = lane & 15, rb = (lane >> 4) * 4;
    #pragma unroll
    for (int mi = 0; mi < 4; ++mi) {
        int o = o0 + wm + mi * 16 + rb;
        float4 bo = *(const float4*)&biasc[o];
        #pragma unroll
        for (int r = 0; r < 4; ++r) {
            float br = (r == 0) ? bo.x : (r == 1) ? bo.y : (r == 2) ? bo.z : bo.w;
            #pragma unroll
            for (int ni = 0; ni < 4; ++ni) {
                int p = p0 + wn + ni * 16 + col;
                Out[(((size_t)(n * 256 + o + r)) << 12) + p] = acc[mi][ni][r] + br;
            }
        }
    }
}

// ---------------------------------------------------------------------------
extern "C" void kernel_launch(void* const* d_in, const int* in_sizes, int n_in,
                              void* d_out, int out_size, void* d_ws, size_t ws_size,
                              hipStream_t stream) {
    const float* x        = (const float*)d_in[0];
    const float* w_exp    = (const float*)d_in[1];
    const float* b_exp    = (const float*)d_in[2];
    const float* w_res    = (const float*)d_in[3];
    const float* b_res    = (const float*)d_in[4];
    const float* w_fus    = (const float*)d_in[5];
    const float* b_fus    = (const float*)d_in[6];
    const float* ch_wv_w  = (const float*)d_in[7];
    const float* ch_wv_b  = (const float*)d_in[8];
    const float* ch_wq_w  = (const float*)d_in[9];
    const float* ch_wq_b  = (const float*)d_in[10];
    const float* ch_wz_w  = (const float*)d_in[11];
    const float* ch_wz_b  = (const float*)d_in[12];
    const float* ln_g     = (const float*)d_in[13];
    const float* ln_b     = (const float*)d_in[14];
    const float* sp_wv_w  = (const float*)d_in[15];
    const float* sp_wv_b  = (const float*)d_in[16];
    const float* sp_wq_w  = (const float*)d_in[17];
    const float* sp_wq_b  = (const float*)d_in[18];
    float* out = (float*)d_out;
    float* ws  = (float*)d_ws;

    // workspace layout (float offsets); total ~19.45M floats ~= 78 MB
    float*    pos   = ws + 0;                      // 1,048,576
    float*    posT  = ws + 1048576;                // 1,048,576
    ushort_t* xbT   = (ushort_t*)(ws + 2097152);   // 8,388,608 ushorts
    ushort_t* exT   = (ushort_t*)(ws + 6291456);   // 25,165,824 ushorts
    ushort_t* wexpb = (ushort_t*)(ws + 18874368);  // 196,608 ushorts
    ushort_t* Wcat  = (ushort_t*)(ws + 18972672);  // 262,144 ushorts
    float*    qdot  = ws + 19103744;   // 98,304
    float*    tbuf  = ws + 19202048;   // 98,304
    float*    spw   = ws + 19300352;   // 98,304
    float*    g     = ws + 19398656;   // 768 (zero region start)
    float*    c0v   = ws + 19399424;   // 4
    float*    ubar  = ws + 19399428;   // 6,144 (zero region end: 6,916 total)
    float*    xba   = ws + 19405572;   // 2,048
    float*    xb6   = ws + 19407620;   // 2,048
    float*    pba   = ws + 19409668;   // 256
    float*    pb6   = ws + 19409924;   // 256
    float*    Mn    = ws + 19410180;   // 24
    float*    iZ    = ws + 19410204;   // 24
    float*    weff  = ws + 19410228;   // 6,144
    float*    btot  = ws + 19416372;   // 24
    float*    hb    = ws + 19416396;   // 6,144
    float*    xq    = ws + 19422540;   // 6,144
    float*    posq  = ws + 19428684;   // 6,144
    float*    chw   = ws + 19434828;   // 6,144
    float*    biasc = ws + 19440972;   // 256

    pos_both<<<4096, 256, 0, stream>>>(pos, posT);
    zero_kernel<<<28, 256, 0, stream>>>(g, 6916);
    trans_x<<<dim3(128, 8, 8), 256, 0, stream>>>(x, xbT);
    conv_bf16<<<768, 256, 0, stream>>>(w_exp, wexpb, 196608);
    prep_g<<<dim3(3, 8), 256, 0, stream>>>(w_exp, b_exp, ch_wq_w, ch_wq_b, g, c0v);
    prep_wcomb<<<dim3(256, 3), 256, 0, stream>>>(w_fus, w_res, b_res, b_fus, Wcat, biasc);

    xbar_kernel<<<dim3(256, 9), 256, 0, stream>>>(x, pos, xba, xb6, pba, pb6);
    qdot_kernel<<<dim3(32, 8), 512, 0, stream>>>(x, pos, g, c0v, ch_wq_w, qdot);
    ubar_split<<<dim3(3, 8, 8), 256, 0, stream>>>(w_exp, b_exp, xba, xb6, pba, pb6, ubar);
    pass_b_h<<<dim3(3, 8), 256, 0, stream>>>(qdot, ubar, sp_wq_w, sp_wq_b,
                                             sp_wv_w, sp_wv_b, w_exp, b_exp,
                                             Mn, iZ, weff, hb, btot);
    spw_t_kernel<<<dim3(32, 8), 512, 0, stream>>>(x, pos, hb, weff, qdot, Mn, iZ,
                                                  btot, spw, tbuf);
    xq_kernel<<<dim3(256, 8), 256, 0, stream>>>(x, pos, tbuf, xq, posq);
    pass_d_uq<<<dim3(3, 8), 256, 0, stream>>>(w_exp, b_exp, xq, posq,
                                              ch_wv_w, ch_wv_b, ch_wz_w, ch_wz_b,
                                              ln_g, ln_b, chw);

    gemm_expT<<<dim3(32, 6, 8), 256, 0, stream>>>(wexpb, xbT, b_exp, posT, chw, spw, exT);
    gemm_out<<<dim3(32, 2, 8), 256, 0, stream>>>(Wcat, xbT, exT, biasc, out);
}

// Round 7
// 291.375 us; speedup vs baseline: 5.7270x; 1.0606x over previous
//
#include <hip/hip_runtime.h>
#include <cstddef>

// ---------------------------------------------------------------------------
// PatchAttention, algebraically simplified + bf16 MFMA GEMMs.
// 8 dispatches: prep_all -> xbar -> qdot+ubar -> pass_b_h -> spw_t(+xq)
//               -> pass_d_uq -> gemm_expT (gated epilogue) -> gemm_out
// ---------------------------------------------------------------------------

#define HW 4096
typedef unsigned short ushort_t;
typedef __attribute__((ext_vector_type(8))) short bf16x8;
typedef __attribute__((ext_vector_type(4))) float floatx4;

__device__ __forceinline__ ushort_t f2bf(float f) {
    unsigned u = __float_as_uint(f);
    u += 0x7FFF + ((u >> 16) & 1);           // RNE
    return (ushort_t)(u >> 16);
}
__device__ __forceinline__ float bf2f(ushort_t h) {
    return __uint_as_float(((unsigned)h) << 16);
}

__device__ __forceinline__ int cnt1f(int y, int sh, int kh, int win) {
    int t = y - kh + sh;
    int lo = t > 0 ? t / sh : 0;
    int hi = min(win - 1, y / sh);
    return hi - lo + 1;
}

__device__ __forceinline__ float posval(int f) {
    int row = f >> 8, col = f & 255;
    int a = row >> 6, b = row & 63;
    int g = col >> 6, k = col & 63;
    float omega = expf(-(float)k * (9.2103403719761836f / 64.f)); // 10000^(-k/64)
    float arg = (g < 2 ? (float)a : (float)b) * omega;
    return (g & 1) ? cosf(arg) : sinf(arg);
}

// ---------------- prep_all: pos/posT, trans_x, conv_bf16, prep_g, prep_wcomb,
// ---------------- zero xq/posq.  13,875 blocks x 256 threads.
__global__ __launch_bounds__(256) void prep_all(
    const float* __restrict__ x, const float* __restrict__ W_exp,
    const float* __restrict__ b_exp, const float* __restrict__ wq,
    const float* __restrict__ wq_b, const float* __restrict__ W_fus,
    const float* __restrict__ W_res, const float* __restrict__ b_res,
    const float* __restrict__ b_fus,
    float* __restrict__ pos, float* __restrict__ posT,
    ushort_t* __restrict__ xbT, ushort_t* __restrict__ wexpb,
    float* __restrict__ g, float* __restrict__ c0out,
    ushort_t* __restrict__ Wcat, float* __restrict__ biasc,
    float* __restrict__ zeroreg)
{
    __shared__ float smf[1184];
    int b = blockIdx.x, tid = threadIdx.x;
    if (b < 4096) {
        int idx = b * 256 + tid;
        pos[idx] = posval(idx);
        int p = idx >> 8, c = idx & 255;
        posT[idx] = posval(c * 4096 + p);
    } else if (b < 12288) {
        int v = b - 4096;
        int p0 = (v & 127) * 32, c0 = ((v >> 7) & 7) * 32, n = v >> 10;
        int cc = tid >> 3, p4 = (tid & 7) * 4;
        const float* src = x + (((size_t)(n * 256 + c0 + cc)) << 12) + p0 + p4;
        float4 vv = *(const float4*)src;
        smf[cc * 37 + p4] = vv.x; smf[cc * 37 + p4 + 1] = vv.y;
        smf[cc * 37 + p4 + 2] = vv.z; smf[cc * 37 + p4 + 3] = vv.w;
        __syncthreads();
        int pp = tid >> 3, c4 = (tid & 7) * 4;
        unsigned lo = (unsigned)f2bf(smf[c4 * 37 + pp]) | ((unsigned)f2bf(smf[(c4 + 1) * 37 + pp]) << 16);
        unsigned hi = (unsigned)f2bf(smf[(c4 + 2) * 37 + pp]) | ((unsigned)f2bf(smf[(c4 + 3) * 37 + pp]) << 16);
        *(uint2*)&xbT[(((size_t)(n << 12)) + p0 + pp) * 256 + c0 + c4] = make_uint2(lo, hi);
    } else if (b < 13056) {
        int i = (b - 12288) * 256 + tid;
        wexpb[i] = f2bf(W_exp[i]);
    } else if (b < 13059) {
        int i = b - 13056;
        float* wql = smf;          // 256
        float* red = smf + 256;    // 256
        wql[tid] = wq[tid];
        red[tid] = wq[tid] * b_exp[i * 256 + tid];
        __syncthreads();
        const float* Wb = W_exp + ((size_t)(i * 256)) * 256 + tid;
        float acc = 0.f;
        #pragma unroll 8
        for (int oc = 0; oc < 256; ++oc) acc = fmaf(wql[oc], Wb[(size_t)oc * 256], acc);
        g[i * 256 + tid] = acc;
        for (int s = 128; s > 0; s >>= 1) { if (tid < s) red[tid] += red[tid + s]; __syncthreads(); }
        if (tid == 0) c0out[i] = red[0] + wq_b[0];
    } else if (b < 13827) {
        int v = b - 13059;
        int o = v & 255, jb = v >> 8;
        float* wrow = smf;         // 256
        float* red = smf + 256;    // 256
        wrow[tid] = W_fus[o * 256 + tid];
        __syncthreads();
        int j = jb * 256 + tid;
        float acc = 0.f;
        #pragma unroll 8
        for (int c = 0; c < 256; ++c) acc = fmaf(wrow[c], W_res[(size_t)c * 768 + j], acc);
        Wcat[o * 1024 + 256 + j] = f2bf(acc);
        if (jb == 0) {
            Wcat[o * 1024 + tid] = f2bf(wrow[tid]);
            red[tid] = wrow[tid] * b_res[tid];
            __syncthreads();
            for (int s = 128; s > 0; s >>= 1) { if (tid < s) red[tid] += red[tid + s]; __syncthreads(); }
            if (tid == 0) biasc[o] = red[0] + b_fus[o];
        }
    } else {
        int i = (b - 13827) * 256 + tid;   // < 12288 (xq ++ posq)
        zeroreg[i] = 0.f;
    }
}

// ------------- xbar (cnt-weighted sums of x rows) + posbar (grid 256 x 9)
__global__ __launch_bounds__(256) void xbar_kernel(
    const float* __restrict__ x, const float* __restrict__ pos,
    float* __restrict__ xbar_all, float* __restrict__ xbar6,
    float* __restrict__ posbar, float* __restrict__ posbar6)
{
    int c = blockIdx.x, n = blockIdx.y, tid = threadIdx.x;
    const float* src = (n < 8) ? x + (((size_t)(n * 256 + c)) << 12)
                               : pos + (((size_t)c) << 12);
    float sa = 0.f, s6 = 0.f;
    #pragma unroll
    for (int k = 0; k < 4; ++k) {
        int f4 = tid + k * 256;
        float4 v = *(const float4*)(src + f4 * 4);
        int p = f4 * 4;
        int y = p >> 6, xx = p & 63;
        float cy = (float)cnt1f(y, 10, 14, 6);
        float c0_ = cy * (float)cnt1f(xx + 0, 10, 14, 6);
        float c1_ = cy * (float)cnt1f(xx + 1, 10, 14, 6);
        float c2_ = cy * (float)cnt1f(xx + 2, 10, 14, 6);
        float c3_ = cy * (float)cnt1f(xx + 3, 10, 14, 6);
        sa += v.x + v.y + v.z + v.w;
        s6 += c0_ * v.x + c1_ * v.y + c2_ * v.z + c3_ * v.w;
    }
    __shared__ float red[256];
    red[tid] = sa; __syncthreads();
    for (int s = 128; s > 0; s >>= 1) { if (tid < s) red[tid] += red[tid + s]; __syncthreads(); }
    float ra = red[0]; __syncthreads();
    red[tid] = s6; __syncthreads();
    for (int s = 128; s > 0; s >>= 1) { if (tid < s) red[tid] += red[tid + s]; __syncthreads(); }
    float r6 = red[0];
    if (tid == 0) {
        if (n < 8) { xbar_all[n * 256 + c] = ra; xbar6[n * 256 + c] = r6; }
        else       { posbar[c] = ra;             posbar6[c] = r6; }
    }
}

// ---- blocks 0..255: qdot (512 thr, 4-way k-split). blocks 256..279: ubar.
__global__ __launch_bounds__(512) void qdot_ubar(
    const float* __restrict__ x, const float* __restrict__ pos,
    const float* __restrict__ g, const float* __restrict__ c0in,
    const float* __restrict__ wq, float* __restrict__ qdot,
    const float* __restrict__ W_exp, const float* __restrict__ b_exp,
    const float* __restrict__ xbar_all, const float* __restrict__ xbar6,
    const float* __restrict__ posbar, const float* __restrict__ posbar6,
    float* __restrict__ ubar)
{
    int blk = blockIdx.x, tid = threadIdx.x;
    if (blk < 256) {
        int n = blk >> 5;
        int ph = tid & 127, cq = tid >> 7;
        int p = (blk & 31) * 128 + ph;
        __shared__ float gl[768];
        __shared__ float wql[256];
        __shared__ float4 red4[512];
        for (int k = tid; k < 768; k += 512) gl[k] = g[k];
        if (tid < 256) wql[tid] = wq[tid];
        __syncthreads();
        const float* xp = x + (((size_t)n) << 20) + p;
        const float* pp = pos + p;
        float q0 = 0.f, q1 = 0.f, q2 = 0.f, qp = 0.f;
        #pragma unroll 4
        for (int c = cq * 64; c < cq * 64 + 64; ++c) {
            float xv = xp[(size_t)c << 12];
            float pv = pp[(size_t)c << 12];
            q0 = fmaf(gl[c], xv, q0);
            q1 = fmaf(gl[256 + c], xv, q1);
            q2 = fmaf(gl[512 + c], xv, q2);
            qp = fmaf(wql[c], pv, qp);
        }
        red4[tid] = make_float4(q0, q1, q2, qp);
        __syncthreads();
        if (tid < 128) {
            float4 a = red4[tid], b = red4[128 + tid], cc = red4[256 + tid], d = red4[384 + tid];
            float rp = a.w + b.w + cc.w + d.w;
            qdot[((0 * 8 + n) << 12) + p] = a.x + b.x + cc.x + d.x + rp + c0in[0];
            qdot[((1 * 8 + n) << 12) + p] = a.y + b.y + cc.y + d.y + rp + c0in[1];
            qdot[((2 * 8 + n) << 12) + p] = a.z + b.z + cc.z + d.z + rp + c0in[2];
        }
    } else {
        int v = blk - 256;
        int i = v >> 3, n = v & 7;
        __shared__ float xbl[256];
        if (tid < 256) xbl[tid] = ((i < 2) ? xbar_all : xbar6)[n * 256 + tid];
        __syncthreads();
        if (tid < 256) {
            int win = 2 * (i + 1), sh = 64 / win, kh = sh + 64 % win;
            float Li = (float)(win * win * kh * kh);
            float acc = b_exp[i * 256 + tid] * Li + ((i < 2) ? posbar : posbar6)[tid];
            const float* Wr = W_exp + ((size_t)(i * 256 + tid)) * 256;
            #pragma unroll 8
            for (int j = 0; j < 256; ++j) acc = fmaf(Wr[j], xbl[j], acc);
            ubar[(i * 8 + n) * 256 + tid] = acc;
        }
    }
}

// ---- softmax stats, spq, w_eff, h, btot (grid 3 x 8)
__global__ __launch_bounds__(256) void pass_b_h(
    const float* __restrict__ qdot, const float* __restrict__ ubar_raw,
    const float* __restrict__ sp_wq_w, const float* __restrict__ sp_wq_b,
    const float* __restrict__ sp_wv_w, const float* __restrict__ sp_wv_b,
    const float* __restrict__ W_exp, const float* __restrict__ b_exp,
    float* __restrict__ Mn, float* __restrict__ invZn,
    float* __restrict__ w_eff, float* __restrict__ h, float* __restrict__ btot)
{
    int i = blockIdx.x, n = blockIdx.y, tid = threadIdx.x;
    int b = i * 8 + n;
    int win = 2 * (i + 1), sh = 64 / win, kh = sh + 64 % win;
    float invL = 1.f / (float)(win * win * kh * kh);
    const float* qd = qdot + (((size_t)b) << 12);
    __shared__ float red[256];
    __shared__ float ub[256];
    __shared__ float spq[128];
    __shared__ float we[256];
    float m = -1e30f;
    for (int p = tid; p < HW; p += 256) m = fmaxf(m, qd[p]);
    red[tid] = m; __syncthreads();
    for (int s = 128; s > 0; s >>= 1) { if (tid < s) red[tid] = fmaxf(red[tid], red[tid + s]); __syncthreads(); }
    float M = red[0]; __syncthreads();
    float z = 0.f;
    for (int p = tid; p < HW; p += 256) {
        int y = p >> 6, xx = p & 63;
        float cf = (float)(cnt1f(y, sh, kh, win) * cnt1f(xx, sh, kh, win));
        z += cf * expf(qd[p] - M);
    }
    red[tid] = z; __syncthreads();
    for (int s = 128; s > 0; s >>= 1) { if (tid < s) red[tid] += red[tid + s]; __syncthreads(); }
    float Z = red[0]; __syncthreads();
    if (tid == 0) { Mn[b] = M; invZn[b] = 1.f / Z; }
    ub[tid] = ubar_raw[b * 256 + tid] * invL;
    __syncthreads();
    float sl = -1e30f;
    if (tid < 128) {
        float a = sp_wq_b[tid];
        #pragma unroll 8
        for (int c = 0; c < 256; ++c) a = fmaf(sp_wq_w[tid * 256 + c], ub[c], a);
        sl = a;
    }
    red[tid] = sl; __syncthreads();
    for (int s = 128; s > 0; s >>= 1) { if (tid < s) red[tid] = fmaxf(red[tid], red[tid + s]); __syncthreads(); }
    float m2 = red[0]; __syncthreads();
    float e = (tid < 128) ? expf(sl - m2) : 0.f;
    red[tid] = e; __syncthreads();
    for (int s = 128; s > 0; s >>= 1) { if (tid < s) red[tid] += red[tid + s]; __syncthreads(); }
    float S2 = red[0]; __syncthreads();
    if (tid < 128) spq[tid] = e / S2;
    __syncthreads();
    float a = 0.f;
    #pragma unroll 8
    for (int c2 = 0; c2 < 128; ++c2) a = fmaf(spq[c2], sp_wv_w[c2 * 256 + tid], a);
    w_eff[b * 256 + tid] = a;
    we[tid] = a;
    red[tid] = (tid < 128) ? spq[tid] * sp_wv_b[tid] : 0.f;
    __syncthreads();
    for (int s = 128; s > 0; s >>= 1) { if (tid < s) red[tid] += red[tid + s]; __syncthreads(); }
    float beff = red[0]; __syncthreads();
    const float* Wb = W_exp + (size_t)i * 65536 + tid;
    float hacc = 0.f;
    #pragma unroll 8
    for (int oc = 0; oc < 256; ++oc) hacc = fmaf(we[oc], Wb[(size_t)oc * 256], hacc);
    h[b * 256 + tid] = hacc;
    red[tid] = we[tid] * b_exp[i * 256 + tid];
    __syncthreads();
    for (int s = 128; s > 0; s >>= 1) { if (tid < s) red[tid] += red[tid + s]; __syncthreads(); }
    if (tid == 0) btot[b] = red[0] + beff;
}

// --- phase1: spw = sigmoid(h.x + weff.pos + btot), t = cnt*softmax(qdot)
// --- phase2: xq[c]  += sum_p t*xbT[p][c]  (bf16), posq[c] += sum_p t*posT[p][c]
__global__ __launch_bounds__(512) void spw_t_xq(
    const float* __restrict__ x, const float* __restrict__ pos,
    const float* __restrict__ h, const float* __restrict__ weff,
    const float* __restrict__ qdot, const float* __restrict__ Mn,
    const float* __restrict__ invZn, const float* __restrict__ btot,
    const ushort_t* __restrict__ xbT, const float* __restrict__ posT,
    float* __restrict__ spw, float* __restrict__ xq, float* __restrict__ posq)
{
    int n = blockIdx.y, tid = threadIdx.x;
    int ph = tid & 127, cq = tid >> 7;
    int p0b = blockIdx.x * 128;
    int p = p0b + ph;
    __shared__ float hl[768], wl[768];
    __shared__ float4 red4[512];
    __shared__ float tl[3][128];
    for (int k = tid; k < 768; k += 512) {
        int i = k >> 8, c = k & 255;
        hl[k] = h[(i * 8 + n) * 256 + c];
        wl[k] = weff[(i * 8 + n) * 256 + c];
    }
    __syncthreads();
    const float* xp = x + (((size_t)n) << 20) + p;
    const float* pp = pos + p;
    float a0 = 0.f, a1 = 0.f, a2 = 0.f;
    #pragma unroll 4
    for (int c = cq * 64; c < cq * 64 + 64; ++c) {
        float xv = xp[(size_t)c << 12];
        float pv = pp[(size_t)c << 12];
        a0 += hl[c] * xv + wl[c] * pv;
        a1 += hl[256 + c] * xv + wl[256 + c] * pv;
        a2 += hl[512 + c] * xv + wl[512 + c] * pv;
    }
    red4[tid] = make_float4(a0, a1, a2, 0.f);
    __syncthreads();
    if (tid < 128) {
        float4 aa = red4[tid], bb = red4[128 + tid], cc = red4[256 + tid], dd = red4[384 + tid];
        float av[3] = {aa.x + bb.x + cc.x + dd.x,
                       aa.y + bb.y + cc.y + dd.y,
                       aa.z + bb.z + cc.z + dd.z};
        int y = p >> 6, xx = p & 63;
        #pragma unroll
        for (int i = 0; i < 3; ++i) {
            int b = i * 8 + n;
            int win = 2 * (i + 1), sh = 64 / win, kh = sh + 64 % win;
            float cf = (float)(cnt1f(y, sh, kh, win) * cnt1f(xx, sh, kh, win));
            int idx = (b << 12) + p;
            spw[idx] = 1.f / (1.f + expf(-(av[i] + btot[b])));
            tl[i][ph] = cf * expf(qdot[idx] - Mn[b]) * invZn[b];
        }
    }
    __syncthreads();
    // phase 2
    int c = tid & 255;
    int half = tid >> 8;
    float s0 = 0.f, s1 = 0.f, s2 = 0.f;
    if (half == 0) {
        const ushort_t* xb = xbT + (((size_t)((n << 12) + p0b)) << 8) + c;
        #pragma unroll 4
        for (int pl = 0; pl < 128; ++pl) {
            float xv = bf2f(xb[(size_t)pl << 8]);
            s0 = fmaf(tl[0][pl], xv, s0);
            s1 = fmaf(tl[1][pl], xv, s1);
            s2 = fmaf(tl[2][pl], xv, s2);
        }
        atomicAdd(&xq[(0 * 8 + n) * 256 + c], s0);
        atomicAdd(&xq[(1 * 8 + n) * 256 + c], s1);
        atomicAdd(&xq[(2 * 8 + n) * 256 + c], s2);
    } else {
        const float* pt = posT + (((size_t)p0b) << 8) + c;
        #pragma unroll 4
        for (int pl = 0; pl < 128; ++pl) {
            float pv = pt[(size_t)pl << 8];
            s0 = fmaf(tl[0][pl], pv, s0);
            s1 = fmaf(tl[1][pl], pv, s1);
            s2 = fmaf(tl[2][pl], pv, s2);
        }
        atomicAdd(&posq[(0 * 8 + n) * 256 + c], s0);
        atomicAdd(&posq[(1 * 8 + n) * 256 + c], s1);
        atomicAdd(&posq[(2 * 8 + n) * 256 + c], s2);
    }
}

// ---- uq = W_exp_i@xq + b + posq; z->wz->LN->sigmoid->chw (grid 3x8)
__global__ __launch_bounds__(256) void pass_d_uq(
    const float* __restrict__ W_exp, const float* __restrict__ b_exp,
    const float* __restrict__ xq, const float* __restrict__ posq,
    const float* __restrict__ ch_wv_w, const float* __restrict__ ch_wv_b,
    const float* __restrict__ ch_wz_w, const float* __restrict__ ch_wz_b,
    const float* __restrict__ ln_g, const float* __restrict__ ln_b,
    float* __restrict__ ch_w)
{
    int i = blockIdx.x, n = blockIdx.y, tid = threadIdx.x;
    int b = i * 8 + n;
    __shared__ float xql[256];
    __shared__ float uql[256];
    __shared__ float zz[128];
    __shared__ float red[256];
    xql[tid] = xq[b * 256 + tid];
    __syncthreads();
    float acc = b_exp[i * 256 + tid] + posq[b * 256 + tid];
    const float* Wr = W_exp + ((size_t)(i * 256 + tid)) * 256;
    #pragma unroll 8
    for (int cin = 0; cin < 256; ++cin) acc = fmaf(Wr[cin], xql[cin], acc);
    uql[tid] = acc;
    __syncthreads();
    if (tid < 128) {
        float a = ch_wv_b[tid];
        #pragma unroll 8
        for (int c = 0; c < 256; ++c) a = fmaf(ch_wv_w[tid * 256 + c], uql[c], a);
        zz[tid] = a;
    }
    __syncthreads();
    float wz = ch_wz_b[tid];
    #pragma unroll 8
    for (int c2 = 0; c2 < 128; ++c2) wz = fmaf(ch_wz_w[tid * 128 + c2], zz[c2], wz);
    red[tid] = wz; __syncthreads();
    for (int s = 128; s > 0; s >>= 1) { if (tid < s) red[tid] += red[tid + s]; __syncthreads(); }
    float mean = red[0] * (1.f / 256.f); __syncthreads();
    float d = wz - mean;
    red[tid] = d * d; __syncthreads();
    for (int s = 128; s > 0; s >>= 1) { if (tid < s) red[tid] += red[tid + s]; __syncthreads(); }
    float var = red[0] * (1.f / 256.f);
    float xn = d / sqrtf(var + 1e-5f);
    ch_w[b * 256 + tid] = 1.f / (1.f + expf(-(xn * ln_g[tid] + ln_b[tid])));
}

// ---- MFMA GEMM 1 (LDS-staged gated epilogue): exT bf16 [n][p][768]
//   e = W_exp@x+b;  combined = e + (e + posT)*(chw + spw)
__global__ __launch_bounds__(256) void gemm_expT(
    const ushort_t* __restrict__ Wb, const ushort_t* __restrict__ XT,
    const float* __restrict__ bias, const float* __restrict__ posT,
    const float* __restrict__ chw, const float* __restrict__ spw,
    ushort_t* __restrict__ OutT)
{
    __shared__ ushort_t SM[10240];           // As | Bs ; reused as stage [128][72]
    ushort_t* As = SM;
    ushort_t* Bs = SM + 5120;
    int n = blockIdx.z;
    int p0 = blockIdx.x * 128;
    int o0 = blockIdx.y * 128;
    int t = threadIdx.x;
    int lane = t & 63, wave = t >> 6;
    int wm = (wave & 1) * 64, wn = (wave >> 1) * 64;
    int lr = lane & 15, lk = (lane >> 4) * 8;
    int ar = t >> 2, ac = (t & 3) * 8;
    const ushort_t* A0 = Wb + (size_t)(o0 + ar) * 256 + ac;
    const ushort_t* A1 = Wb + (size_t)(o0 + ar + 64) * 256 + ac;
    const ushort_t* B0 = XT + (((size_t)(n << 12)) + p0 + ar) * 256 + ac;
    const ushort_t* B1 = XT + (((size_t)(n << 12)) + p0 + ar + 64) * 256 + ac;
    floatx4 acc[4][4] = {};
    for (int k0 = 0; k0 < 256; k0 += 32) {
        uint4 a0 = *(const uint4*)(A0 + k0);
        uint4 a1 = *(const uint4*)(A1 + k0);
        uint4 b0 = *(const uint4*)(B0 + k0);
        uint4 b1 = *(const uint4*)(B1 + k0);
        __syncthreads();
        *(uint4*)&As[ar * 40 + ac] = a0;
        *(uint4*)&As[(ar + 64) * 40 + ac] = a1;
        *(uint4*)&Bs[ar * 40 + ac] = b0;
        *(uint4*)&Bs[(ar + 64) * 40 + ac] = b1;
        __syncthreads();
        bf16x8 af[4], bfr[4];
        #pragma unroll
        for (int mi = 0; mi < 4; ++mi)
            af[mi] = *(const bf16x8*)&As[(wm + mi * 16 + lr) * 40 + lk];
        #pragma unroll
        for (int ni = 0; ni < 4; ++ni)
            bfr[ni] = *(const bf16x8*)&Bs[(wn + ni * 16 + lr) * 40 + lk];
        #pragma unroll
        for (int mi = 0; mi < 4; ++mi)
            #pragma unroll
            for (int ni = 0; ni < 4; ++ni)
                acc[mi][ni] = __builtin_amdgcn_mfma_f32_16x16x32_bf16(
                    af[mi], bfr[ni], acc[mi][ni], 0, 0, 0);
    }
    int col = lane & 15, rb = (lane >> 4) * 4;
    int ibr = o0 >> 8;
    int bi = ibr * 8 + n;
    #pragma unroll
    for (int r = 0; r < 2; ++r) {
        __syncthreads();
        if (wm == r * 64) {
            #pragma unroll
            for (int mi = 0; mi < 4; ++mi) {
                int o_loc = mi * 16 + rb;
                float4 bo = *(const float4*)&bias[o0 + r * 64 + o_loc];
                #pragma unroll
                for (int ni = 0; ni < 4; ++ni) {
                    int prow = wn + ni * 16 + col;
                    floatx4 v = acc[mi][ni];
                    unsigned lo = (unsigned)f2bf(v[0] + bo.x) | ((unsigned)f2bf(v[1] + bo.y) << 16);
                    unsigned hi = (unsigned)f2bf(v[2] + bo.z) | ((unsigned)f2bf(v[3] + bo.w) << 16);
                    *(uint2*)&SM[prow * 72 + o_loc] = make_uint2(lo, hi);
                }
            }
        }
        __syncthreads();
        #pragma unroll
        for (int it = 0; it < 4; ++it) {
            int slot = it * 256 + t;
            int pl = slot >> 3, j = (slot & 7) * 8;
            uint4 raw = *(const uint4*)&SM[pl * 72 + j];
            float e0 = bf2f((ushort_t)(raw.x & 0xFFFF)), e1 = bf2f((ushort_t)(raw.x >> 16));
            float e2 = bf2f((ushort_t)(raw.y & 0xFFFF)), e3 = bf2f((ushort_t)(raw.y >> 16));
            float e4 = bf2f((ushort_t)(raw.z & 0xFFFF)), e5 = bf2f((ushort_t)(raw.z >> 16));
            float e6 = bf2f((ushort_t)(raw.w & 0xFFFF)), e7 = bf2f((ushort_t)(raw.w >> 16));
            int p = p0 + pl;
            int cbase = (o0 & 255) + r * 64 + j;
            float s = spw[(bi << 12) + p];
            float4 q0 = *(const float4*)&posT[p * 256 + cbase];
            float4 q1 = *(const float4*)&posT[p * 256 + cbase + 4];
            float4 w0 = *(const float4*)&chw[bi * 256 + cbase];
            float4 w1 = *(const float4*)&chw[bi * 256 + cbase + 4];
            float r0 = e0 + (e0 + q0.x) * (w0.x + s);
            float r1 = e1 + (e1 + q0.y) * (w0.y + s);
            float r2 = e2 + (e2 + q0.z) * (w0.z + s);
            float r3 = e3 + (e3 + q0.w) * (w0.w + s);
            float r4 = e4 + (e4 + q1.x) * (w1.x + s);
            float r5 = e5 + (e5 + q1.y) * (w1.y + s);
            float r6 = e6 + (e6 + q1.z) * (w1.z + s);
            float r7 = e7 + (e7 + q1.w) * (w1.w + s);
            uint4 outv;
            outv.x = (unsigned)f2bf(r0) | ((unsigned)f2bf(r1) << 16);
            outv.y = (unsigned)f2bf(r2) | ((unsigned)f2bf(r3) << 16);
            outv.z = (unsigned)f2bf(r4) | ((unsigned)f2bf(r5) << 16);
            outv.w = (unsigned)f2bf(r6) | ((unsigned)f2bf(r7) << 16);
            *(uint4*)&OutT[(((size_t)(n << 12)) + p) * 768 + o0 + r * 64 + j] = outv;
        }
    }
}

// ---- MFMA GEMM 2: out = Wcat @ [x ; combined] + biasc, fp32 [n][256][4096]
__global__ __launch_bounds__(256) void gemm_out(
    const ushort_t* __restrict__ Wcat, const ushort_t* __restrict__ XT,
    const ushort_t* __restrict__ CT, const float* __restrict__ biasc,
    float* __restrict__ Out)
{
    __shared__ ushort_t As[128 * 40];
    __shared__ ushort_t Bs[128 * 40];
    int n = blockIdx.z;
    int p0 = blockIdx.x * 128;
    int o0 = blockIdx.y * 128;
    int t = threadIdx.x;
    int lane = t & 63, wave = t >> 6;
    int wm = (wave & 1) * 64, wn = (wave >> 1) * 64;
    int lr = lane & 15, lk = (lane >> 4) * 8;
    int ar = t >> 2, ac = (t & 3) * 8;
    const ushort_t* A0 = Wcat + (size_t)(o0 + ar) * 1024 + ac;
    const ushort_t* A1 = Wcat + (size_t)(o0 + ar + 64) * 1024 + ac;
    const ushort_t* BX0 = XT + (((size_t)(n << 12)) + p0 + ar) * 256 + ac;
    const ushort_t* BX1 = XT + (((size_t)(n << 12)) + p0 + ar + 64) * 256 + ac;
    const ushort_t* BC0 = CT + (((size_t)(n << 12)) + p0 + ar) * 768 + ac;
    const ushort_t* BC1 = CT + (((size_t)(n << 12)) + p0 + ar + 64) * 768 + ac;
    floatx4 acc[4][4] = {};
    for (int k0 = 0; k0 < 1024; k0 += 32) {
        const ushort_t* pb0 = (k0 < 256) ? (BX0 + k0) : (BC0 + (k0 - 256));
        const ushort_t* pb1 = (k0 < 256) ? (BX1 + k0) : (BC1 + (k0 - 256));
        uint4 a0 = *(const uint4*)(A0 + k0);
        uint4 a1 = *(const uint4*)(A1 + k0);
        uint4 b0 = *(const uint4*)pb0;
        uint4 b1 = *(const uint4*)pb1;
        __syncthreads();
        *(uint4*)&As[ar * 40 + ac] = a0;
        *(uint4*)&As[(ar + 64) * 40 + ac] = a1;
        *(uint4*)&Bs[ar * 40 + ac] = b0;
        *(uint4*)&Bs[(ar + 64) * 40 + ac] = b1;
        __syncthreads();
        bf16x8 af[4], bfr[4];
        #pragma unroll
        for (int mi = 0; mi < 4; ++mi)
            af[mi] = *(const bf16x8*)&As[(wm + mi * 16 + lr) * 40 + lk];
        #pragma unroll
        for (int ni = 0; ni < 4; ++ni)
            bfr[ni] = *(const bf16x8*)&Bs[(wn + ni * 16 + lr) * 40 + lk];
        #pragma unroll
        for (int mi = 0; mi < 4; ++mi)
            #pragma unroll
            for (int ni = 0; ni < 4; ++ni)
                acc[mi][ni] = __builtin_amdgcn_mfma_f32_16x16x32_bf16(
                    af[mi], bfr[ni], acc[mi][ni], 0, 0, 0);
    }
    int col = lane & 15, rb = (lane >> 4) * 4;
    #pragma unroll
    for (int mi = 0; mi < 4; ++mi) {
        int o = o0 + wm + mi * 16 + rb;
        float4 bo = *(const float4*)&biasc[o];
        #pragma unroll
        for (int r = 0; r < 4; ++r) {
            float br = (r == 0) ? bo.x : (r == 1) ? bo.y : (r == 2) ? bo.z : bo.w;
            #pragma unroll
            for (int ni = 0; ni < 4; ++ni) {
                int p = p0 + wn + ni * 16 + col;
                Out[(((size_t)(n * 256 + o + r)) << 12) + p] = acc[mi][ni][r] + br;
            }
        }
    }
}

// ---------------------------------------------------------------------------
extern "C" void kernel_launch(void* const* d_in, const int* in_sizes, int n_in,
                              void* d_out, int out_size, void* d_ws, size_t ws_size,
                              hipStream_t stream) {
    const float* x        = (const float*)d_in[0];
    const float* w_exp    = (const float*)d_in[1];
    const float* b_exp    = (const float*)d_in[2];
    const float* w_res    = (const float*)d_in[3];
    const float* b_res    = (const float*)d_in[4];
    const float* w_fus    = (const float*)d_in[5];
    const float* b_fus    = (const float*)d_in[6];
    const float* ch_wv_w  = (const float*)d_in[7];
    const float* ch_wv_b  = (const float*)d_in[8];
    const float* ch_wq_w  = (const float*)d_in[9];
    const float* ch_wq_b  = (const float*)d_in[10];
    const float* ch_wz_w  = (const float*)d_in[11];
    const float* ch_wz_b  = (const float*)d_in[12];
    const float* ln_g     = (const float*)d_in[13];
    const float* ln_b     = (const float*)d_in[14];
    const float* sp_wv_w  = (const float*)d_in[15];
    const float* sp_wv_b  = (const float*)d_in[16];
    const float* sp_wq_w  = (const float*)d_in[17];
    const float* sp_wq_b  = (const float*)d_in[18];
    float* out = (float*)d_out;
    float* ws  = (float*)d_ws;

    // workspace layout (float offsets)
    float*    pos   = ws + 0;                      // 1,048,576
    float*    posT  = ws + 1048576;                // 1,048,576
    ushort_t* xbT   = (ushort_t*)(ws + 2097152);   // 8,388,608 ushorts
    ushort_t* exT   = (ushort_t*)(ws + 6291456);   // 25,165,824 ushorts
    ushort_t* wexpb = (ushort_t*)(ws + 18874368);  // 196,608 ushorts
    ushort_t* Wcat  = (ushort_t*)(ws + 18972672);  // 262,144 ushorts
    float*    qdot  = ws + 19103744;   // 98,304
    float*    spw   = ws + 19300352;   // 98,304
    float*    g     = ws + 19398656;   // 768
    float*    c0v   = ws + 19399424;   // 4
    float*    ubar  = ws + 19399428;   // 6,144
    float*    xba   = ws + 19405572;   // 2,048
    float*    xb6   = ws + 19407620;   // 2,048
    float*    pba   = ws + 19409668;   // 256
    float*    pb6   = ws + 19409924;   // 256
    float*    Mn    = ws + 19410180;   // 24
    float*    iZ    = ws + 19410204;   // 24
    float*    weff  = ws + 19410228;   // 6,144
    float*    btot  = ws + 19416372;   // 24
    float*    hb    = ws + 19416396;   // 6,144
    float*    xq    = ws + 19422540;   // 6,144  (zeroed in prep_all)
    float*    posq  = ws + 19428684;   // 6,144  (zeroed in prep_all)
    float*    chw   = ws + 19434828;   // 6,144
    float*    biasc = ws + 19440972;   // 256

    prep_all<<<13875, 256, 0, stream>>>(x, w_exp, b_exp, ch_wq_w, ch_wq_b,
                                        w_fus, w_res, b_res, b_fus,
                                        pos, posT, xbT, wexpb, g, c0v,
                                        Wcat, biasc, xq);
    xbar_kernel<<<dim3(256, 9), 256, 0, stream>>>(x, pos, xba, xb6, pba, pb6);
    qdot_ubar<<<280, 512, 0, stream>>>(x, pos, g, c0v, ch_wq_w, qdot,
                                       w_exp, b_exp, xba, xb6, pba, pb6, ubar);
    pass_b_h<<<dim3(3, 8), 256, 0, stream>>>(qdot, ubar, sp_wq_w, sp_wq_b,
                                             sp_wv_w, sp_wv_b, w_exp, b_exp,
                                             Mn, iZ, weff, hb, btot);
    spw_t_xq<<<dim3(32, 8), 512, 0, stream>>>(x, pos, hb, weff, qdot, Mn, iZ,
                                              btot, xbT, posT, spw, xq, posq);
    pass_d_uq<<<dim3(3, 8), 256, 0, stream>>>(w_exp, b_exp, xq, posq,
                                              ch_wv_w, ch_wv_b, ch_wz_w, ch_wz_b,
                                              ln_g, ln_b, chw);
    gemm_expT<<<dim3(32, 6, 8), 256, 0, stream>>>(wexpb, xbT, b_exp, posT, chw, spw, exT);
    gemm_out<<<dim3(32, 2, 8), 256, 0, stream>>>(Wcat, xbT, exT, biasc, out);
}